// Round 5
// baseline (1730.639 us; speedup 1.0000x reference)
//
#include <hip/hip_runtime.h>
#include <math.h>

#define BATCH 16
#define CCH   512
#define HWS   4096                 // H*W
#define CHW   (CCH*HWS)            // per-batch elements: 2,097,152
#define DHFF  2048
#define NHEAD 8
#define HD    64
#define QKVLD 1536
#define LNEPS 1e-5f

typedef unsigned short u16;
typedef __bf16 bf16x8 __attribute__((ext_vector_type(8)));
typedef float f32x4 __attribute__((ext_vector_type(4)));

// tanh-form GELU via sigmoid identity: 0.5x(1+tanh(y)) = x*sigmoid(2y).
__device__ __forceinline__ float gelu_f(float x) {
    float y = 1.5957691216057308f * x * (1.0f + 0.044715f * x * x);
    return x / (1.0f + __expf(-y));
}
__device__ __forceinline__ u16 f2bf(float f) {
    union { float f; unsigned u; } c; c.f = f;
    unsigned r = c.u + 0x7FFFu + ((c.u >> 16) & 1u);
    return (u16)(r >> 16);
}
__device__ __forceinline__ float bf2f(u16 h) {
    union { unsigned u; float f; } c; c.u = ((unsigned)h) << 16; return c.f;
}
// direct global->LDS 16B copy; lds base must be wave-uniform (HW: base + lane*16)
__device__ __forceinline__ void gld16(const u16* g, u16* l) {
    __builtin_amdgcn_global_load_lds((const __attribute__((address_space(1))) unsigned*)g,
                                     (__attribute__((address_space(3))) unsigned*)l, 16, 0, 0);
}

// ---------- per-batch sum/sumsq over x (LN1 stats) ----------
__global__ __launch_bounds__(256) void stats_k(const float* __restrict__ src,
                                               float* __restrict__ st) {
    int b = blockIdx.y;
    const float4* p = (const float4*)(src + (size_t)b * CHW + (size_t)blockIdx.x * (CHW / 64));
    float s = 0.f, ss = 0.f;
    for (int i = threadIdx.x; i < (CHW / 64 / 4); i += 256) {
        float4 v = p[i];
        s  += v.x + v.y + v.z + v.w;
        ss += v.x * v.x + v.y * v.y + v.z * v.z + v.w * v.w;
    }
    __shared__ float r1[256], r2[256];
    int t = threadIdx.x;
    r1[t] = s; r2[t] = ss; __syncthreads();
    for (int o = 128; o > 0; o >>= 1) {
        if (t < o) { r1[t] += r1[t + o]; r2[t] += r2[t + o]; }
        __syncthreads();
    }
    if (t == 0) { atomicAdd(&st[2 * b], r1[0]); atomicAdd(&st[2 * b + 1], r2[0]); }
}

// ---------- fp32 -> bf16 flat convert (weights) ----------
__global__ __launch_bounds__(256) void cvt_k(const float* __restrict__ src,
                                             u16* __restrict__ dst, int n4) {
    int i = blockIdx.x * 256 + threadIdx.x;
    if (i >= n4) return;
    float4 v = ((const float4*)src)[i];
    uint2 o; u16* op = (u16*)&o;
    op[0] = f2bf(v.x); op[1] = f2bf(v.y); op[2] = f2bf(v.z); op[3] = f2bf(v.w);
    ((uint2*)dst)[i] = o;
}

// ---------- fp32 [c][p] -> fp32 [p][c] transpose (ln2 w/b) ----------
__global__ __launch_bounds__(256) void tr_k(const float* __restrict__ src,
                                            float* __restrict__ dst) {
    int p0 = blockIdx.x * 32, c0 = blockIdx.y * 32;
    __shared__ float T[32][33];
    int tx = threadIdx.x & 31, ty = threadIdx.x >> 5;
#pragma unroll
    for (int i = 0; i < 4; ++i)
        T[ty + i * 8][tx] = src[(size_t)(c0 + ty + i * 8) * HWS + p0 + tx];
    __syncthreads();
#pragma unroll
    for (int i = 0; i < 4; ++i)
        dst[(size_t)(p0 + ty + i * 8) * CCH + c0 + tx] = T[tx][ty + i * 8];
}

// ---------- LN1 + transpose + cvt: a[p][c] bf16 = LN1(x)[c][p] ----------
__global__ __launch_bounds__(256) void ln1t_k(const float* __restrict__ x,
                                              const float* __restrict__ w,
                                              const float* __restrict__ bb,
                                              const float* __restrict__ st,
                                              u16* __restrict__ a, int cb) {
    int p0 = blockIdx.x * 32, c0 = blockIdx.y * 32, bl = blockIdx.z;
    int b = cb + bl;
    float mean = st[2 * b] * (1.0f / CHW);
    float var  = st[2 * b + 1] * (1.0f / CHW) - mean * mean;
    float rstd = rsqrtf(var + LNEPS);
    __shared__ float T[32][33];
    int tx = threadIdx.x & 31, ty = threadIdx.x >> 5;
    const float* xb = x + (size_t)b * CHW;
#pragma unroll
    for (int i = 0; i < 4; ++i) {
        size_t o = (size_t)(c0 + ty + i * 8) * HWS + p0 + tx;
        T[ty + i * 8][tx] = (xb[o] - mean) * rstd * w[o] + bb[o];
    }
    __syncthreads();
    u16* ab = a + (size_t)bl * CHW;
#pragma unroll
    for (int i = 0; i < 4; ++i)
        ab[(size_t)(p0 + ty + i * 8) * CCH + c0 + tx] = f2bf(T[tx][ty + i * 8]);
}

// ---------- bf16 MFMA GEMM (TN): Out[m][n] = sum_k A[m][k]*B[n][k] + bias[n] ----------
// 128x128 tile, BK=32, 256 thr = 4 waves. 2-phase double-buffered LDS:
// prefetch k+1 into buf^1 BEFORE compute of k; single barrier AFTER MFMA so the
// vmcnt drain (implicit in __syncthreads) is hidden under compute.
template<int ACT, int OBF>
__global__ __launch_bounds__(256) void gemm_tn(const u16* __restrict__ A,
                                               const u16* __restrict__ B,
                                               const float* __restrict__ bias,
                                               void* __restrict__ Out,
                                               int K, int ldo, int nt) {
    __shared__ u16 As[2][128 * 32];
    __shared__ u16 Bs[2][128 * 32];
    const int tid = threadIdx.x;
    // XCD swizzle: grid %8 == 0 for all call sites; n-tile fastest within chunk.
    const int cpx = gridDim.x >> 3;
    const int wg = (blockIdx.x & 7) * cpx + (blockIdx.x >> 3);
    const int m0 = (wg / nt) * 128;
    const int n0 = (wg % nt) * 128;
    const int lane = tid & 63;
    const int w = tid >> 6;
    const int wm = (w & 1) * 64, wn = (w >> 1) * 64;
    const int ls = lane & 15, lq = lane >> 4;

    f32x4 acc[4][4];
#pragma unroll
    for (int i = 0; i < 4; ++i)
#pragma unroll
        for (int j = 0; j < 4; ++j) acc[i][j] = (f32x4){0.f, 0.f, 0.f, 0.f};

    // staging map: wave w stages rows [w*16, w*16+16) and +64; lane covers 16B chunk
    const int srow = w * 16 + (lane >> 2);      // 0..63
    const int scol = (lane & 3) * 8;            // u16 col within 32
    const u16* gA0 = A + (size_t)(m0 + srow) * K + scol;
    const u16* gA1 = gA0 + (size_t)64 * K;
    const u16* gB0 = B + (size_t)(n0 + srow) * K + scol;
    const u16* gB1 = gB0 + (size_t)64 * K;
    const int lo = w * 512;                     // wave-uniform LDS offset

    // prologue: stage k-step 0 into buffer 0, wait, cross barrier
    gld16(gA0, &As[0][lo]);
    gld16(gA1, &As[0][2048 + lo]);
    gld16(gB0, &Bs[0][lo]);
    gld16(gB1, &Bs[0][2048 + lo]);
    __syncthreads();

    int cur = 0;
    for (int kt = 0; kt < K; kt += 32) {
        if (kt + 32 < K) {                      // issue next-tile loads FIRST
            int nx = cur ^ 1;
            gld16(gA0 + kt + 32, &As[nx][lo]);
            gld16(gA1 + kt + 32, &As[nx][2048 + lo]);
            gld16(gB0 + kt + 32, &Bs[nx][lo]);
            gld16(gB1 + kt + 32, &Bs[nx][2048 + lo]);
        }
        bf16x8 af[4], bfv[4];
#pragma unroll
        for (int i = 0; i < 4; ++i)
            af[i] = *(bf16x8*)&As[cur][(wm + i * 16 + ls) * 32 + lq * 8];
#pragma unroll
        for (int j = 0; j < 4; ++j)
            bfv[j] = *(bf16x8*)&Bs[cur][(wn + j * 16 + ls) * 32 + lq * 8];
#pragma unroll
        for (int i = 0; i < 4; ++i)
#pragma unroll
            for (int j = 0; j < 4; ++j)
                acc[i][j] = __builtin_amdgcn_mfma_f32_16x16x32_bf16(bfv[j], af[i], acc[i][j], 0, 0, 0);
        if (kt + 32 < K) {
            __syncthreads();                    // drains vmcnt AFTER compute -> next buf ready
            cur ^= 1;
        }
    }

    // swapped epilogue: lane holds rows n = n0+wn+j*16+lq*4+r, col m = m0+wm+i*16+ls
#pragma unroll
    for (int j = 0; j < 4; ++j) {
        int nb = n0 + wn + j * 16 + lq * 4;
        float4 bv = *(const float4*)&bias[nb];
#pragma unroll
        for (int i = 0; i < 4; ++i) {
            int m = m0 + wm + i * 16 + ls;
            float v0 = acc[i][j][0] + bv.x;
            float v1 = acc[i][j][1] + bv.y;
            float v2 = acc[i][j][2] + bv.z;
            float v3 = acc[i][j][3] + bv.w;
            if (ACT) { v0 = gelu_f(v0); v1 = gelu_f(v1); v2 = gelu_f(v2); v3 = gelu_f(v3); }
            size_t idx = (size_t)m * ldo + nb;
            if (OBF) {
                uint2 o; u16* op = (u16*)&o;
                op[0] = f2bf(v0); op[1] = f2bf(v1); op[2] = f2bf(v2); op[3] = f2bf(v3);
                *(uint2*)((u16*)Out + idx) = o;
            } else {
                *(float4*)((float*)Out + idx) = (float4){v0, v1, v2, v3};
            }
        }
    }
}

// ---------- softmax over Q channels (cols 0..511 of QKV rows), per pixel ----------
__global__ __launch_bounds__(256) void softmax_row_k(u16* __restrict__ QKV) {
    int m = blockIdx.x * 4 + (threadIdx.x >> 6);
    int lane = threadIdx.x & 63;
    u16* row = QKV + (size_t)m * QKVLD + lane * 8;
    uint4 raw = *(uint4*)row;
    u16* pr = (u16*)&raw;
    float v[8];
#pragma unroll
    for (int i = 0; i < 8; ++i) v[i] = bf2f(pr[i]);
    float mx = v[0];
#pragma unroll
    for (int i = 1; i < 8; ++i) mx = fmaxf(mx, v[i]);
    for (int o = 32; o > 0; o >>= 1) mx = fmaxf(mx, __shfl_xor(mx, o, 64));
    float s = 0.f;
#pragma unroll
    for (int i = 0; i < 8; ++i) { v[i] = __expf(v[i] - mx); s += v[i]; }
    for (int o = 32; o > 0; o >>= 1) s += __shfl_xor(s, o, 64);
    float inv = 1.0f / s;
#pragma unroll
    for (int i = 0; i < 8; ++i) pr[i] = f2bf(v[i] * inv);
    *(uint4*)row = raw;
}

// ---------- K-column softmax partial stats: per (b, 256-row chunk), per column ----------
__global__ __launch_bounds__(256) void kcolstat_k(const u16* __restrict__ QKV,
                                                  float* __restrict__ kpart) {
    int pc = blockIdx.x, bl = blockIdx.y;
    int cg = threadIdx.x & 63;           // column group (8 cols)
    int ps = threadIdx.x >> 6;           // p segment 0..3 (64 rows each)
    const u16* base = QKV + (size_t)bl * HWS * QKVLD + CCH + cg * 8;
    int p0 = pc * 256 + ps * 64;
    float m[8];
#pragma unroll
    for (int i = 0; i < 8; ++i) m[i] = -1e30f;
    for (int p = p0; p < p0 + 64; ++p) {
        uint4 r = *(const uint4*)(base + (size_t)p * QKVLD);
        u16* rp = (u16*)&r;
#pragma unroll
        for (int i = 0; i < 8; ++i) m[i] = fmaxf(m[i], bf2f(rp[i]));
    }
    __shared__ float red[4][512];
#pragma unroll
    for (int i = 0; i < 8; ++i) red[ps][cg * 8 + i] = m[i];
    __syncthreads();
#pragma unroll
    for (int i = 0; i < 8; ++i)
        m[i] = fmaxf(fmaxf(red[0][cg * 8 + i], red[1][cg * 8 + i]),
                     fmaxf(red[2][cg * 8 + i], red[3][cg * 8 + i]));
    __syncthreads();
    float s[8];
#pragma unroll
    for (int i = 0; i < 8; ++i) s[i] = 0.f;
    for (int p = p0; p < p0 + 64; ++p) {      // L2-hot second pass
        uint4 r = *(const uint4*)(base + (size_t)p * QKVLD);
        u16* rp = (u16*)&r;
#pragma unroll
        for (int i = 0; i < 8; ++i) s[i] += __expf(bf2f(rp[i]) - m[i]);
    }
#pragma unroll
    for (int i = 0; i < 8; ++i) red[ps][cg * 8 + i] = s[i];
    __syncthreads();
    if (ps == 0) {
        float* outp = kpart + (((size_t)bl * 16 + pc) * 512 + cg * 8) * 2;
#pragma unroll
        for (int i = 0; i < 8; ++i) {
            float sv = red[0][cg * 8 + i] + red[1][cg * 8 + i] +
                       red[2][cg * 8 + i] + red[3][cg * 8 + i];
            outp[2 * i] = m[i]; outp[2 * i + 1] = sv;
        }
    }
}

// ---------- merge 16 chunk partials -> (max, 1/sum) per column ----------
__global__ __launch_bounds__(256) void kcolmerge_k(const float* __restrict__ kpart,
                                                   float* __restrict__ kstat) {
    int bl = blockIdx.x;
#pragma unroll
    for (int j = 0; j < 2; ++j) {
        int col = threadIdx.x * 2 + j;
        float m = -1e30f;
        for (int pc = 0; pc < 16; ++pc)
            m = fmaxf(m, kpart[(((size_t)bl * 16 + pc) * 512 + col) * 2]);
        float s = 0.f;
        for (int pc = 0; pc < 16; ++pc) {
            const float* p = kpart + (((size_t)bl * 16 + pc) * 512 + col) * 2;
            s += p[1] * __expf(p[0] - m);
        }
        kstat[((size_t)bl * 512 + col) * 2]     = m;
        kstat[((size_t)bl * 512 + col) * 2 + 1] = 1.0f / s;
    }
}

// ---------- KV[b,h,k,v] = sum_p softmaxK[p][hk]*V[p][hv] (atomic over 16 p-chunks) ----------
__global__ __launch_bounds__(256) void kv_k2(const u16* __restrict__ QKV,
                                             const float* __restrict__ kstat,
                                             float* __restrict__ KV) {
    int pc = blockIdx.x, h = blockIdx.y, bl = blockIdx.z;
    const u16* kbase = QKV + (size_t)bl * HWS * QKVLD + CCH + h * HD;
    const u16* vbase = kbase + CCH;
    float* kvb = KV + ((size_t)bl * NHEAD + h) * (HD * HD);
    __shared__ float Ks[64][65], Vs[64][65];
    __shared__ float Ms[64], Is[64];
    int tid = threadIdx.x;
    if (tid < 64) {
        const float* sp = kstat + ((size_t)bl * 512 + h * HD + tid) * 2;
        Ms[tid] = sp[0]; Is[tid] = sp[1];
    }
    int tk = tid >> 4, tv = tid & 15;
    float acc[4][4];
#pragma unroll
    for (int i = 0; i < 4; ++i)
#pragma unroll
        for (int j = 0; j < 4; ++j) acc[i][j] = 0.f;

    for (int s = 0; s < 4; ++s) {
        int pbase = pc * 256 + s * 64;
        __syncthreads();
#pragma unroll
        for (int j = 0; j < 2; ++j) {
            int li = tid + j * 256;
            int pl = li >> 3, c8 = (li & 7) * 8;
            uint4 kr = *(const uint4*)(kbase + (size_t)(pbase + pl) * QKVLD + c8);
            uint4 vr = *(const uint4*)(vbase + (size_t)(pbase + pl) * QKVLD + c8);
            u16* kp = (u16*)&kr; u16* vp = (u16*)&vr;
#pragma unroll
            for (int t = 0; t < 8; ++t) {
                Ks[pl][c8 + t] = __expf(bf2f(kp[t]) - Ms[c8 + t]) * Is[c8 + t];
                Vs[pl][c8 + t] = bf2f(vp[t]);
            }
        }
        __syncthreads();
#pragma unroll 4
        for (int p = 0; p < 64; ++p) {
            float ka[4], va[4];
#pragma unroll
            for (int i = 0; i < 4; ++i) { ka[i] = Ks[p][tk * 4 + i]; va[i] = Vs[p][tv * 4 + i]; }
#pragma unroll
            for (int i = 0; i < 4; ++i)
#pragma unroll
                for (int j = 0; j < 4; ++j) acc[i][j] += ka[i] * va[j];
        }
    }
#pragma unroll
    for (int i = 0; i < 4; ++i)
#pragma unroll
        for (int j = 0; j < 4; ++j)
            atomicAdd(&kvb[(size_t)(tk * 4 + i) * HD + tv * 4 + j], acc[i][j]);
}

// ---------- attnRaw[p][hv] bf16 = sum_k KV[k][v]*Q[p][hk] ----------
__global__ __launch_bounds__(256) void attn_k2(const u16* __restrict__ QKV,
                                               const float* __restrict__ KV,
                                               u16* __restrict__ attnRaw) {
    int pt = blockIdx.x, h = blockIdx.y, bl = blockIdx.z;
    const u16* qbase = QKV + (size_t)bl * HWS * QKVLD + h * HD;
    const float* kvb = KV + ((size_t)bl * NHEAD + h) * (HD * HD);
    __shared__ float KVs[64][68], Qs[64][68];
    int tid = threadIdx.x;
#pragma unroll
    for (int j = 0; j < 4; ++j) {
        int li = tid + j * 256;
        int k = li >> 4, c4 = (li & 15) * 4;
        *(float4*)&KVs[k][c4] = *(const float4*)(kvb + (size_t)k * HD + c4);
    }
#pragma unroll
    for (int j = 0; j < 2; ++j) {
        int li = tid + j * 256;
        int pl = li >> 3, c8 = (li & 7) * 8;
        uint4 qr = *(const uint4*)(qbase + (size_t)(pt * 64 + pl) * QKVLD + c8);
        u16* qp = (u16*)&qr;
#pragma unroll
        for (int t = 0; t < 8; ++t) Qs[pl][c8 + t] = bf2f(qp[t]);
    }
    __syncthreads();
    int tp = tid >> 4, tv = tid & 15;
    float acc[4][4];
#pragma unroll
    for (int i = 0; i < 4; ++i)
#pragma unroll
        for (int j = 0; j < 4; ++j) acc[i][j] = 0.f;
#pragma unroll 4
    for (int k = 0; k < 64; ++k) {
        float qa[4], kv4[4];
#pragma unroll
        for (int i = 0; i < 4; ++i) { qa[i] = Qs[tp * 4 + i][k]; kv4[i] = KVs[k][tv * 4 + i]; }
#pragma unroll
        for (int i = 0; i < 4; ++i)
#pragma unroll
            for (int j = 0; j < 4; ++j) acc[i][j] += qa[i] * kv4[j];
    }
#pragma unroll
    for (int i = 0; i < 4; ++i) {
        uint2 wv; u16* wp = (u16*)&wv;
#pragma unroll
        for (int j = 0; j < 4; ++j) wp[j] = f2bf(acc[i][j]);
        *(uint2*)(attnRaw + (size_t)(bl * HWS + pt * 64 + tp * 4 + i) * CCH + h * HD + tv * 4) = wv;
    }
}

// ---------- r[p][c] = x[c][p] + attnOut[p][c], per-block LN2 partial stats ----------
__global__ __launch_bounds__(256) void resid_t_k(const float* __restrict__ x,
                                                 const float* __restrict__ ao,
                                                 float* __restrict__ r,
                                                 float* __restrict__ pstat, int cb) {
    int p0 = blockIdx.x * 32, c0 = blockIdx.y * 32, bl = blockIdx.z;
    int b = cb + bl;
    __shared__ float T[32][33];
    __shared__ float r1[256], r2[256];
    int tx = threadIdx.x & 31, ty = threadIdx.x >> 5;
    const float* xb = x + (size_t)b * CHW;
#pragma unroll
    for (int i = 0; i < 4; ++i)
        T[ty + i * 8][tx] = xb[(size_t)(c0 + ty + i * 8) * HWS + p0 + tx];
    __syncthreads();
    float s = 0.f, ss = 0.f;
#pragma unroll
    for (int i = 0; i < 4; ++i) {
        size_t o = (size_t)bl * CHW + (size_t)(p0 + ty + i * 8) * CCH + c0 + tx;
        float v = T[tx][ty + i * 8] + ao[o];
        r[o] = v; s += v; ss += v * v;
    }
    int t = threadIdx.x;
    r1[t] = s; r2[t] = ss; __syncthreads();
    for (int o = 128; o > 0; o >>= 1) {
        if (t < o) { r1[t] += r1[t + o]; r2[t] += r2[t + o]; }
        __syncthreads();
    }
    if (t == 0) {
        float* pp = pstat + ((size_t)b * 2048 + (size_t)blockIdx.x * 16 + blockIdx.y) * 2;
        pp[0] = r1[0]; pp[1] = r2[0];
    }
}

// ---------- reduce 2048 per-block partials -> LN2 stats (plain store) ----------
__global__ __launch_bounds__(256) void red2_k(const float* __restrict__ pstat,
                                              float* __restrict__ st, int cb) {
    int b = cb + blockIdx.x;
    const float* p = pstat + (size_t)b * 4096;
    float s = 0.f, ss = 0.f;
    for (int i = threadIdx.x; i < 2048; i += 256) {
        s += p[2 * i]; ss += p[2 * i + 1];
    }
    __shared__ float r1[256], r2[256];
    int t = threadIdx.x;
    r1[t] = s; r2[t] = ss; __syncthreads();
    for (int o = 128; o > 0; o >>= 1) {
        if (t < o) { r1[t] += r1[t + o]; r2[t] += r2[t + o]; }
        __syncthreads();
    }
    if (t == 0) { st[32 + 2 * b] = r1[0]; st[32 + 2 * b + 1] = r2[0]; }
}

// ---------- x2 bf16 [p][c] = LN2(r) ----------
__global__ __launch_bounds__(256) void ln2a_k(const float* __restrict__ r,
                                              const float* __restrict__ w2t,
                                              const float* __restrict__ b2t,
                                              const float* __restrict__ st,
                                              u16* __restrict__ x2, int cb) {
    size_t i4 = (size_t)blockIdx.x * 256 + threadIdx.x;
    int bl = (int)(i4 / (CHW / 4));
    int b = cb + bl;
    size_t off4 = i4 % (CHW / 4);
    float mean = st[32 + 2 * b] * (1.0f / CHW);
    float var  = st[32 + 2 * b + 1] * (1.0f / CHW) - mean * mean;
    float rstd = rsqrtf(var + LNEPS);
    float4 v  = ((const float4*)(r + (size_t)bl * CHW))[off4];
    float4 wv = ((const float4*)w2t)[off4];
    float4 bv = ((const float4*)b2t)[off4];
    uint2 o; u16* op = (u16*)&o;
    op[0] = f2bf((v.x - mean) * rstd * wv.x + bv.x);
    op[1] = f2bf((v.y - mean) * rstd * wv.y + bv.y);
    op[2] = f2bf((v.z - mean) * rstd * wv.z + bv.z);
    op[3] = f2bf((v.w - mean) * rstd * wv.w + bv.w);
    ((uint2*)(x2 + (size_t)bl * CHW))[off4] = o;
}

// ---------- out[c][p] = x2[p][c] + ffOut[p][c] (transpose back) ----------
__global__ __launch_bounds__(256) void final_t_k(const u16* __restrict__ x2,
                                                 const float* __restrict__ ffo,
                                                 float* __restrict__ out, int cb) {
    int c0 = blockIdx.x * 32, p0 = blockIdx.y * 32, bl = blockIdx.z;
    int b = cb + bl;
    __shared__ float T[32][33];
    int tx = threadIdx.x & 31, ty = threadIdx.x >> 5;
#pragma unroll
    for (int i = 0; i < 4; ++i) {
        size_t o = (size_t)bl * CHW + (size_t)(p0 + ty + i * 8) * CCH + c0 + tx;
        T[ty + i * 8][tx] = ffo[o] + bf2f(x2[o]);   // T[p_local][c_local]
    }
    __syncthreads();
    float* ob = out + (size_t)b * CHW;
#pragma unroll
    for (int i = 0; i < 4; ++i)
        ob[(size_t)(c0 + ty + i * 8) * HWS + p0 + tx] = T[tx][ty + i * 8];
}

extern "C" void kernel_launch(void* const* d_in, const int* in_sizes, int n_in,
                              void* d_out, int out_size, void* d_ws, size_t ws_size,
                              hipStream_t stream) {
    const float* x    = (const float*)d_in[0];
    const float* ln1w = (const float*)d_in[1];
    const float* ln1b = (const float*)d_in[2];
    const float* qw   = (const float*)d_in[3];
    const float* qb   = (const float*)d_in[4];
    const float* kw   = (const float*)d_in[5];
    const float* kb   = (const float*)d_in[6];
    const float* vw   = (const float*)d_in[7];
    const float* vb   = (const float*)d_in[8];
    const float* huw  = (const float*)d_in[9];
    const float* hub  = (const float*)d_in[10];
    const float* ln2w = (const float*)d_in[11];
    const float* ln2b = (const float*)d_in[12];
    const float* f1w  = (const float*)d_in[13];
    const float* f1b  = (const float*)d_in[14];
    const float* f2w  = (const float*)d_in[15];
    const float* f2b  = (const float*)d_in[16];
    float* out = (float*)d_out;
    float* ws = (float*)d_ws;

    // fixed ws region (floats)
    float* stats = ws;                      // 64
    float* qkvb  = ws + 64;                 // 1536
    u16*   wqkv  = (u16*)(ws + 1600);       // 1536x512 bf16 -> 393216 f
    u16*   whu   = (u16*)(ws + 394816);     // 512x512        -> 131072 f
    u16*   wf1   = (u16*)(ws + 525888);     // 2048x512       -> 524288 f
    u16*   wf2   = (u16*)(ws + 1050176);    // 512x2048       -> 524288 f
    float* w2t   = ws + 1574464;            // 2097152 f
    float* b2t   = ws + 3671616;            // 2097152 f
    float* pstat = ws + 5768768;            // 16*2048*2 = 65536 f (LN2 partials)
    float* kpart = ws + 5834304;            // 16*16*512*2 = 262144 f (K col partials)
    float* kstat = ws + 6096448;            // 16*512*2 = 16384 f (K col m,inv)
    float* kvbuf = ws + 6112832;            // G*32768 f

    // chunk size G: fixed(6112832) + G*32768 + region 3.5*G*2097152
    int G = 16;
    while (G > 1 && (6112832ull + (size_t)G * 7372800ull) * 4ull > ws_size) G >>= 1;
    const int nch = BATCH / G;
    const size_t U = (size_t)G * CHW;       // chunk elems (== floats for fp32 bufs)

    float* R       = kvbuf + (size_t)G * 32768;
    u16*   a_bf    = (u16*)R;               // CHWg bf16 (also attnRaw)
    u16*   QKVb    = (u16*)(R + U / 2);     // 3*CHWg bf16
    float* attnOut = R + U / 2;             // CHWg f32 (overlays QKV after attn)
    float* rbuf    = R + 3 * U / 2;         // CHWg f32
    u16*   x2bf    = (u16*)R;               // CHWg bf16 (overlays attnRaw)
    u16*   Hbuf    = (u16*)(R + U / 2);     // 4*CHWg bf16 (overlays attnOut,r)
    float* ffOut   = R + 5 * U / 2;         // CHWg f32

    hipMemsetAsync(stats, 0, 64 * sizeof(float), stream);

    // weight conversions (every call; inputs restored by harness each iter)
    cvt_k<<<dim3(256), 256, 0, stream>>>(qw, wqkv, 65536);
    cvt_k<<<dim3(256), 256, 0, stream>>>(kw, wqkv + 262144, 65536);
    cvt_k<<<dim3(256), 256, 0, stream>>>(vw, wqkv + 524288, 65536);
    cvt_k<<<dim3(256), 256, 0, stream>>>(huw, whu, 65536);
    cvt_k<<<dim3(1024), 256, 0, stream>>>(f1w, wf1, 262144);
    cvt_k<<<dim3(1024), 256, 0, stream>>>(f2w, wf2, 262144);
    tr_k<<<dim3(128, 16), 256, 0, stream>>>(ln2w, w2t);
    tr_k<<<dim3(128, 16), 256, 0, stream>>>(ln2b, b2t);
    hipMemcpyAsync(qkvb,        qb, 512 * sizeof(float), hipMemcpyDeviceToDevice, stream);
    hipMemcpyAsync(qkvb + 512,  kb, 512 * sizeof(float), hipMemcpyDeviceToDevice, stream);
    hipMemcpyAsync(qkvb + 1024, vb, 512 * sizeof(float), hipMemcpyDeviceToDevice, stream);

    stats_k<<<dim3(64, BATCH), 256, 0, stream>>>(x, stats);

    for (int g = 0; g < nch; ++g) {
        const int cb = g * G;
        const int mt = G * 32;   // m-tiles (M = G*4096)
        // LN1 + transpose + cvt -> a[p][c] bf16
        ln1t_k<<<dim3(128, 16, G), 256, 0, stream>>>(x, ln1w, ln1b, stats, a_bf, cb);
        // fused QKV GEMM: [G*4096 x 512] x [1536 x 512]^T -> bf16 [m][1536]
        gemm_tn<0, 1><<<dim3(mt * 12), 256, 0, stream>>>(a_bf, wqkv, qkvb, QKVb, CCH, QKVLD, 12);
        softmax_row_k<<<dim3(G * 1024), 256, 0, stream>>>(QKVb);
        // K column softmax stats (normalization fused into kv_k2)
        kcolstat_k<<<dim3(16, G), 256, 0, stream>>>(QKVb, kpart);
        kcolmerge_k<<<dim3(G), 256, 0, stream>>>(kpart, kstat);
        hipMemsetAsync(kvbuf, 0, (size_t)G * 32768 * sizeof(float), stream);
        kv_k2<<<dim3(16, NHEAD, G), 256, 0, stream>>>(QKVb, kstat, kvbuf);
        attn_k2<<<dim3(64, NHEAD, G), 256, 0, stream>>>(QKVb, kvbuf, a_bf);  // attnRaw over a
        // hu GEMM -> attnOut fp32 [m][512]
        gemm_tn<0, 0><<<dim3(mt * 4), 256, 0, stream>>>(a_bf, whu, hub, attnOut, CCH, CCH, 4);
        resid_t_k<<<dim3(128, 16, G), 256, 0, stream>>>(x, attnOut, rbuf, pstat, cb);
        red2_k<<<dim3(G), 256, 0, stream>>>(pstat, stats, cb);
        ln2a_k<<<dim3(G * 2048), 256, 0, stream>>>(rbuf, w2t, b2t, stats, x2bf, cb);
        // ff1 GEMM + gelu -> H bf16 [m][2048]
        gemm_tn<1, 1><<<dim3(mt * 16), 256, 0, stream>>>(x2bf, wf1, f1b, Hbuf, CCH, DHFF, 16);
        // ff2 GEMM -> ffOut fp32 [m][512]
        gemm_tn<0, 0><<<dim3(mt * 4), 256, 0, stream>>>(Hbuf, wf2, f2b, ffOut, DHFF, CCH, 4);
        // out[c][p] = x2 + ff
        final_t_k<<<dim3(16, 128, G), 256, 0, stream>>>(x2bf, ffOut, out, cb);
    }
}

// Round 6
// 1499.598 us; speedup vs baseline: 1.1541x; 1.1541x over previous
//
#include <hip/hip_runtime.h>
#include <math.h>

#define BATCH 16
#define CCH   512
#define HWS   4096                 // H*W
#define CHW   (CCH*HWS)            // per-batch elements: 2,097,152
#define DHFF  2048
#define NHEAD 8
#define HD    64
#define QKVLD 1536
#define LNEPS 1e-5f

typedef unsigned short u16;
typedef __bf16 bf16x8 __attribute__((ext_vector_type(8)));
typedef float f32x4 __attribute__((ext_vector_type(4)));

// tanh-form GELU via sigmoid identity: 0.5x(1+tanh(y)) = x*sigmoid(2y).
__device__ __forceinline__ float gelu_f(float x) {
    float y = 1.5957691216057308f * x * (1.0f + 0.044715f * x * x);
    return x / (1.0f + __expf(-y));
}
__device__ __forceinline__ u16 f2bf(float f) {
    union { float f; unsigned u; } c; c.f = f;
    unsigned r = c.u + 0x7FFFu + ((c.u >> 16) & 1u);
    return (u16)(r >> 16);
}
__device__ __forceinline__ float bf2f(u16 h) {
    union { unsigned u; float f; } c; c.u = ((unsigned)h) << 16; return c.f;
}
// direct global->LDS 16B copy; lds base must be wave-uniform (HW: base + lane*16)
__device__ __forceinline__ void gld16(const u16* g, u16* l) {
    __builtin_amdgcn_global_load_lds((const __attribute__((address_space(1))) unsigned*)g,
                                     (__attribute__((address_space(3))) unsigned*)l, 16, 0, 0);
}

// ---------- per-batch sum/sumsq over x (LN1 stats) ----------
__global__ __launch_bounds__(256) void stats_k(const float* __restrict__ src,
                                               float* __restrict__ st) {
    int b = blockIdx.y;
    const float4* p = (const float4*)(src + (size_t)b * CHW + (size_t)blockIdx.x * (CHW / 64));
    float s = 0.f, ss = 0.f;
    for (int i = threadIdx.x; i < (CHW / 64 / 4); i += 256) {
        float4 v = p[i];
        s  += v.x + v.y + v.z + v.w;
        ss += v.x * v.x + v.y * v.y + v.z * v.z + v.w * v.w;
    }
    __shared__ float r1[256], r2[256];
    int t = threadIdx.x;
    r1[t] = s; r2[t] = ss; __syncthreads();
    for (int o = 128; o > 0; o >>= 1) {
        if (t < o) { r1[t] += r1[t + o]; r2[t] += r2[t + o]; }
        __syncthreads();
    }
    if (t == 0) { atomicAdd(&st[2 * b], r1[0]); atomicAdd(&st[2 * b + 1], r2[0]); }
}

// ---------- fp32 -> bf16 flat convert (weights) ----------
__global__ __launch_bounds__(256) void cvt_k(const float* __restrict__ src,
                                             u16* __restrict__ dst, int n4) {
    int i = blockIdx.x * 256 + threadIdx.x;
    if (i >= n4) return;
    float4 v = ((const float4*)src)[i];
    uint2 o; u16* op = (u16*)&o;
    op[0] = f2bf(v.x); op[1] = f2bf(v.y); op[2] = f2bf(v.z); op[3] = f2bf(v.w);
    ((uint2*)dst)[i] = o;
}

// ---------- fp32 [c][p] -> fp32 [p][c] transpose (ln2 w/b) ----------
__global__ __launch_bounds__(256) void tr_k(const float* __restrict__ src,
                                            float* __restrict__ dst) {
    int p0 = blockIdx.x * 32, c0 = blockIdx.y * 32;
    __shared__ float T[32][33];
    int tx = threadIdx.x & 31, ty = threadIdx.x >> 5;
#pragma unroll
    for (int i = 0; i < 4; ++i)
        T[ty + i * 8][tx] = src[(size_t)(c0 + ty + i * 8) * HWS + p0 + tx];
    __syncthreads();
#pragma unroll
    for (int i = 0; i < 4; ++i)
        dst[(size_t)(p0 + ty + i * 8) * CCH + c0 + tx] = T[tx][ty + i * 8];
}

// ---------- LN1 + transpose + cvt: a[p][c] bf16 = LN1(x)[c][p] ----------
__global__ __launch_bounds__(256) void ln1t_k(const float* __restrict__ x,
                                              const float* __restrict__ w,
                                              const float* __restrict__ bb,
                                              const float* __restrict__ st,
                                              u16* __restrict__ a, int cb) {
    int p0 = blockIdx.x * 32, c0 = blockIdx.y * 32, bl = blockIdx.z;
    int b = cb + bl;
    float mean = st[2 * b] * (1.0f / CHW);
    float var  = st[2 * b + 1] * (1.0f / CHW) - mean * mean;
    float rstd = rsqrtf(var + LNEPS);
    __shared__ float T[32][33];
    int tx = threadIdx.x & 31, ty = threadIdx.x >> 5;
    const float* xb = x + (size_t)b * CHW;
#pragma unroll
    for (int i = 0; i < 4; ++i) {
        size_t o = (size_t)(c0 + ty + i * 8) * HWS + p0 + tx;
        T[ty + i * 8][tx] = (xb[o] - mean) * rstd * w[o] + bb[o];
    }
    __syncthreads();
    u16* ab = a + (size_t)bl * CHW;
#pragma unroll
    for (int i = 0; i < 4; ++i)
        ab[(size_t)(p0 + ty + i * 8) * CCH + c0 + tx] = f2bf(T[tx][ty + i * 8]);
}

// ---------- bf16 MFMA GEMM (TN): Out[m][n] = sum_k A[m][k]*B[n][k] + bias[n] ----------
// 128x128 tile, BK=32, 256 thr = 4 waves. Compile-time K -> fully static
// double-buffer (r5 lesson: runtime cur-indexing blew up VALU). Schedule per
// step (T3 minimum): issue STAGE(next buf) FIRST, ds_read cur, MFMA, one
// barrier (drains vmcnt+lgkm). Loads stay in flight under compute.
template<int K, int ACT, int OBF>
__global__ __launch_bounds__(256) void gemm_tn(const u16* __restrict__ A,
                                               const u16* __restrict__ B,
                                               const float* __restrict__ bias,
                                               void* __restrict__ Out,
                                               int ldo, int nt) {
    __shared__ u16 As[2][128 * 32];
    __shared__ u16 Bs[2][128 * 32];
    const int tid = threadIdx.x;
    // XCD swizzle: grid %8 == 0 for all call sites; n-tile fastest within chunk.
    const int cpx = gridDim.x >> 3;
    const int wg = (blockIdx.x & 7) * cpx + (blockIdx.x >> 3);
    const int m0 = (wg / nt) * 128;
    const int n0 = (wg % nt) * 128;
    const int lane = tid & 63;
    const int w = tid >> 6;
    const int wm = (w & 1) * 64, wn = (w >> 1) * 64;
    const int ls = lane & 15, lq = lane >> 4;

    f32x4 acc[4][4];
#pragma unroll
    for (int i = 0; i < 4; ++i)
#pragma unroll
        for (int j = 0; j < 4; ++j) acc[i][j] = (f32x4){0.f, 0.f, 0.f, 0.f};

    // staging map: wave w stages rows [w*16, w*16+16) and +64; lane covers 16B chunk
    const int srow = w * 16 + (lane >> 2);      // 0..63
    const int scol = (lane & 3) * 8;            // u16 col within 32
    const u16* gA0 = A + (size_t)(m0 + srow) * K + scol;
    const u16* gA1 = gA0 + (size_t)64 * K;
    const u16* gB0 = B + (size_t)(n0 + srow) * K + scol;
    const u16* gB1 = gB0 + (size_t)64 * K;
    const int lo = w * 512;                     // wave-uniform LDS offset

    // prologue: stage step 0 into buffer 0
    gld16(gA0, &As[0][lo]);
    gld16(gA1, &As[0][2048 + lo]);
    gld16(gB0, &Bs[0][lo]);
    gld16(gB1, &Bs[0][2048 + lo]);
    __syncthreads();

#pragma unroll 8
    for (int kt = 0; kt < K; kt += 32) {
        const int cur = (kt >> 5) & 1;          // compile-time under even unroll
        const int nx = cur ^ 1;
        if (kt + 32 < K) {                      // issue next-step loads FIRST
            gld16(gA0 + kt + 32, &As[nx][lo]);
            gld16(gA1 + kt + 32, &As[nx][2048 + lo]);
            gld16(gB0 + kt + 32, &Bs[nx][lo]);
            gld16(gB1 + kt + 32, &Bs[nx][2048 + lo]);
        }
        bf16x8 af[4], bfv[4];
#pragma unroll
        for (int i = 0; i < 4; ++i)
            af[i] = *(bf16x8*)&As[cur][(wm + i * 16 + ls) * 32 + lq * 8];
#pragma unroll
        for (int j = 0; j < 4; ++j)
            bfv[j] = *(bf16x8*)&Bs[cur][(wn + j * 16 + ls) * 32 + lq * 8];
#pragma unroll
        for (int i = 0; i < 4; ++i)
#pragma unroll
            for (int j = 0; j < 4; ++j)
                acc[i][j] = __builtin_amdgcn_mfma_f32_16x16x32_bf16(bfv[j], af[i], acc[i][j], 0, 0, 0);
        if (kt + 32 < K)
            __syncthreads();                    // drains vmcnt -> next buffer ready
    }

    // swapped epilogue: lane holds rows n = n0+wn+j*16+lq*4+r, col m = m0+wm+i*16+ls
#pragma unroll
    for (int j = 0; j < 4; ++j) {
        int nb = n0 + wn + j * 16 + lq * 4;
        float4 bv = *(const float4*)&bias[nb];
#pragma unroll
        for (int i = 0; i < 4; ++i) {
            int m = m0 + wm + i * 16 + ls;
            float v0 = acc[i][j][0] + bv.x;
            float v1 = acc[i][j][1] + bv.y;
            float v2 = acc[i][j][2] + bv.z;
            float v3 = acc[i][j][3] + bv.w;
            if (ACT) { v0 = gelu_f(v0); v1 = gelu_f(v1); v2 = gelu_f(v2); v3 = gelu_f(v3); }
            size_t idx = (size_t)m * ldo + nb;
            if (OBF) {
                uint2 o; u16* op = (u16*)&o;
                op[0] = f2bf(v0); op[1] = f2bf(v1); op[2] = f2bf(v2); op[3] = f2bf(v3);
                *(uint2*)((u16*)Out + idx) = o;
            } else {
                *(float4*)((float*)Out + idx) = (float4){v0, v1, v2, v3};
            }
        }
    }
}

// ---------- softmax over Q channels (cols 0..511 of QKV rows), per pixel ----------
__global__ __launch_bounds__(256) void softmax_row_k(u16* __restrict__ QKV) {
    int m = blockIdx.x * 4 + (threadIdx.x >> 6);
    int lane = threadIdx.x & 63;
    u16* row = QKV + (size_t)m * QKVLD + lane * 8;
    uint4 raw = *(uint4*)row;
    u16* pr = (u16*)&raw;
    float v[8];
#pragma unroll
    for (int i = 0; i < 8; ++i) v[i] = bf2f(pr[i]);
    float mx = v[0];
#pragma unroll
    for (int i = 1; i < 8; ++i) mx = fmaxf(mx, v[i]);
    for (int o = 32; o > 0; o >>= 1) mx = fmaxf(mx, __shfl_xor(mx, o, 64));
    float s = 0.f;
#pragma unroll
    for (int i = 0; i < 8; ++i) { v[i] = __expf(v[i] - mx); s += v[i]; }
    for (int o = 32; o > 0; o >>= 1) s += __shfl_xor(s, o, 64);
    float inv = 1.0f / s;
#pragma unroll
    for (int i = 0; i < 8; ++i) pr[i] = f2bf(v[i] * inv);
    *(uint4*)row = raw;
}

// ---------- K-column softmax partial stats: per (b, 256-row chunk), per column ----------
__global__ __launch_bounds__(256) void kcolstat_k(const u16* __restrict__ QKV,
                                                  float* __restrict__ kpart) {
    int pc = blockIdx.x, bl = blockIdx.y;
    int cg = threadIdx.x & 63;           // column group (8 cols)
    int ps = threadIdx.x >> 6;           // p segment 0..3 (64 rows each)
    const u16* base = QKV + (size_t)bl * HWS * QKVLD + CCH + cg * 8;
    int p0 = pc * 256 + ps * 64;
    float m[8];
#pragma unroll
    for (int i = 0; i < 8; ++i) m[i] = -1e30f;
    for (int p = p0; p < p0 + 64; ++p) {
        uint4 r = *(const uint4*)(base + (size_t)p * QKVLD);
        u16* rp = (u16*)&r;
#pragma unroll
        for (int i = 0; i < 8; ++i) m[i] = fmaxf(m[i], bf2f(rp[i]));
    }
    __shared__ float red[4][512];
#pragma unroll
    for (int i = 0; i < 8; ++i) red[ps][cg * 8 + i] = m[i];
    __syncthreads();
#pragma unroll
    for (int i = 0; i < 8; ++i)
        m[i] = fmaxf(fmaxf(red[0][cg * 8 + i], red[1][cg * 8 + i]),
                     fmaxf(red[2][cg * 8 + i], red[3][cg * 8 + i]));
    __syncthreads();
    float s[8];
#pragma unroll
    for (int i = 0; i < 8; ++i) s[i] = 0.f;
    for (int p = p0; p < p0 + 64; ++p) {      // L2-hot second pass
        uint4 r = *(const uint4*)(base + (size_t)p * QKVLD);
        u16* rp = (u16*)&r;
#pragma unroll
        for (int i = 0; i < 8; ++i) s[i] += __expf(bf2f(rp[i]) - m[i]);
    }
#pragma unroll
    for (int i = 0; i < 8; ++i) red[ps][cg * 8 + i] = s[i];
    __syncthreads();
    if (ps == 0) {
        float* outp = kpart + (((size_t)bl * 16 + pc) * 512 + cg * 8) * 2;
#pragma unroll
        for (int i = 0; i < 8; ++i) {
            float sv = red[0][cg * 8 + i] + red[1][cg * 8 + i] +
                       red[2][cg * 8 + i] + red[3][cg * 8 + i];
            outp[2 * i] = m[i]; outp[2 * i + 1] = sv;
        }
    }
}

// ---------- merge 16 chunk partials -> (max, 1/sum) per column ----------
__global__ __launch_bounds__(256) void kcolmerge_k(const float* __restrict__ kpart,
                                                   float* __restrict__ kstat) {
    int bl = blockIdx.x;
#pragma unroll
    for (int j = 0; j < 2; ++j) {
        int col = threadIdx.x * 2 + j;
        float m = -1e30f;
        for (int pc = 0; pc < 16; ++pc)
            m = fmaxf(m, kpart[(((size_t)bl * 16 + pc) * 512 + col) * 2]);
        float s = 0.f;
        for (int pc = 0; pc < 16; ++pc) {
            const float* p = kpart + (((size_t)bl * 16 + pc) * 512 + col) * 2;
            s += p[1] * __expf(p[0] - m);
        }
        kstat[((size_t)bl * 512 + col) * 2]     = m;
        kstat[((size_t)bl * 512 + col) * 2 + 1] = 1.0f / s;
    }
}

// ---------- KV[b,h,k,v] = sum_p softmaxK[p][hk]*V[p][hv] (atomic over 16 p-chunks) ----------
__global__ __launch_bounds__(256) void kv_k2(const u16* __restrict__ QKV,
                                             const float* __restrict__ kstat,
                                             float* __restrict__ KV) {
    int pc = blockIdx.x, h = blockIdx.y, bl = blockIdx.z;
    const u16* kbase = QKV + (size_t)bl * HWS * QKVLD + CCH + h * HD;
    const u16* vbase = kbase + CCH;
    float* kvb = KV + ((size_t)bl * NHEAD + h) * (HD * HD);
    __shared__ float Ks[64][65], Vs[64][65];
    __shared__ float Ms[64], Is[64];
    int tid = threadIdx.x;
    if (tid < 64) {
        const float* sp = kstat + ((size_t)bl * 512 + h * HD + tid) * 2;
        Ms[tid] = sp[0]; Is[tid] = sp[1];
    }
    int tk = tid >> 4, tv = tid & 15;
    float acc[4][4];
#pragma unroll
    for (int i = 0; i < 4; ++i)
#pragma unroll
        for (int j = 0; j < 4; ++j) acc[i][j] = 0.f;

    for (int s = 0; s < 4; ++s) {
        int pbase = pc * 256 + s * 64;
        __syncthreads();
#pragma unroll
        for (int j = 0; j < 2; ++j) {
            int li = tid + j * 256;
            int pl = li >> 3, c8 = (li & 7) * 8;
            uint4 kr = *(const uint4*)(kbase + (size_t)(pbase + pl) * QKVLD + c8);
            uint4 vr = *(const uint4*)(vbase + (size_t)(pbase + pl) * QKVLD + c8);
            u16* kp = (u16*)&kr; u16* vp = (u16*)&vr;
#pragma unroll
            for (int t = 0; t < 8; ++t) {
                Ks[pl][c8 + t] = __expf(bf2f(kp[t]) - Ms[c8 + t]) * Is[c8 + t];
                Vs[pl][c8 + t] = bf2f(vp[t]);
            }
        }
        __syncthreads();
#pragma unroll 4
        for (int p = 0; p < 64; ++p) {
            float ka[4], va[4];
#pragma unroll
            for (int i = 0; i < 4; ++i) { ka[i] = Ks[p][tk * 4 + i]; va[i] = Vs[p][tv * 4 + i]; }
#pragma unroll
            for (int i = 0; i < 4; ++i)
#pragma unroll
                for (int j = 0; j < 4; ++j) acc[i][j] += ka[i] * va[j];
        }
    }
#pragma unroll
    for (int i = 0; i < 4; ++i)
#pragma unroll
        for (int j = 0; j < 4; ++j)
            atomicAdd(&kvb[(size_t)(tk * 4 + i) * HD + tv * 4 + j], acc[i][j]);
}

// ---------- attnRaw[p][hv] bf16 = sum_k KV[k][v]*Q[p][hk] ----------
__global__ __launch_bounds__(256) void attn_k2(const u16* __restrict__ QKV,
                                               const float* __restrict__ KV,
                                               u16* __restrict__ attnRaw) {
    int pt = blockIdx.x, h = blockIdx.y, bl = blockIdx.z;
    const u16* qbase = QKV + (size_t)bl * HWS * QKVLD + h * HD;
    const float* kvb = KV + ((size_t)bl * NHEAD + h) * (HD * HD);
    __shared__ float KVs[64][68], Qs[64][68];
    int tid = threadIdx.x;
#pragma unroll
    for (int j = 0; j < 4; ++j) {
        int li = tid + j * 256;
        int k = li >> 4, c4 = (li & 15) * 4;
        *(float4*)&KVs[k][c4] = *(const float4*)(kvb + (size_t)k * HD + c4);
    }
#pragma unroll
    for (int j = 0; j < 2; ++j) {
        int li = tid + j * 256;
        int pl = li >> 3, c8 = (li & 7) * 8;
        uint4 qr = *(const uint4*)(qbase + (size_t)(pt * 64 + pl) * QKVLD + c8);
        u16* qp = (u16*)&qr;
#pragma unroll
        for (int t = 0; t < 8; ++t) Qs[pl][c8 + t] = bf2f(qp[t]);
    }
    __syncthreads();
    int tp = tid >> 4, tv = tid & 15;
    float acc[4][4];
#pragma unroll
    for (int i = 0; i < 4; ++i)
#pragma unroll
        for (int j = 0; j < 4; ++j) acc[i][j] = 0.f;
#pragma unroll 4
    for (int k = 0; k < 64; ++k) {
        float qa[4], kv4[4];
#pragma unroll
        for (int i = 0; i < 4; ++i) { qa[i] = Qs[tp * 4 + i][k]; kv4[i] = KVs[k][tv * 4 + i]; }
#pragma unroll
        for (int i = 0; i < 4; ++i)
#pragma unroll
            for (int j = 0; j < 4; ++j) acc[i][j] += qa[i] * kv4[j];
    }
#pragma unroll
    for (int i = 0; i < 4; ++i) {
        uint2 wv; u16* wp = (u16*)&wv;
#pragma unroll
        for (int j = 0; j < 4; ++j) wp[j] = f2bf(acc[i][j]);
        *(uint2*)(attnRaw + (size_t)(bl * HWS + pt * 64 + tp * 4 + i) * CCH + h * HD + tv * 4) = wv;
    }
}

// ---------- r[p][c] = x[c][p] + attnOut[p][c], per-block LN2 partial stats ----------
__global__ __launch_bounds__(256) void resid_t_k(const float* __restrict__ x,
                                                 const float* __restrict__ ao,
                                                 float* __restrict__ r,
                                                 float* __restrict__ pstat, int cb) {
    int p0 = blockIdx.x * 32, c0 = blockIdx.y * 32, bl = blockIdx.z;
    int b = cb + bl;
    __shared__ float T[32][33];
    __shared__ float r1[256], r2[256];
    int tx = threadIdx.x & 31, ty = threadIdx.x >> 5;
    const float* xb = x + (size_t)b * CHW;
#pragma unroll
    for (int i = 0; i < 4; ++i)
        T[ty + i * 8][tx] = xb[(size_t)(c0 + ty + i * 8) * HWS + p0 + tx];
    __syncthreads();
    float s = 0.f, ss = 0.f;
#pragma unroll
    for (int i = 0; i < 4; ++i) {
        size_t o = (size_t)bl * CHW + (size_t)(p0 + ty + i * 8) * CCH + c0 + tx;
        float v = T[tx][ty + i * 8] + ao[o];
        r[o] = v; s += v; ss += v * v;
    }
    int t = threadIdx.x;
    r1[t] = s; r2[t] = ss; __syncthreads();
    for (int o = 128; o > 0; o >>= 1) {
        if (t < o) { r1[t] += r1[t + o]; r2[t] += r2[t + o]; }
        __syncthreads();
    }
    if (t == 0) {
        float* pp = pstat + ((size_t)b * 2048 + (size_t)blockIdx.x * 16 + blockIdx.y) * 2;
        pp[0] = r1[0]; pp[1] = r2[0];
    }
}

// ---------- reduce 2048 per-block partials -> LN2 stats (plain store) ----------
__global__ __launch_bounds__(256) void red2_k(const float* __restrict__ pstat,
                                              float* __restrict__ st, int cb) {
    int b = cb + blockIdx.x;
    const float* p = pstat + (size_t)b * 4096;
    float s = 0.f, ss = 0.f;
    for (int i = threadIdx.x; i < 2048; i += 256) {
        s += p[2 * i]; ss += p[2 * i + 1];
    }
    __shared__ float r1[256], r2[256];
    int t = threadIdx.x;
    r1[t] = s; r2[t] = ss; __syncthreads();
    for (int o = 128; o > 0; o >>= 1) {
        if (t < o) { r1[t] += r1[t + o]; r2[t] += r2[t + o]; }
        __syncthreads();
    }
    if (t == 0) { st[32 + 2 * b] = r1[0]; st[32 + 2 * b + 1] = r2[0]; }
}

// ---------- x2 bf16 [p][c] = LN2(r) ----------
__global__ __launch_bounds__(256) void ln2a_k(const float* __restrict__ r,
                                              const float* __restrict__ w2t,
                                              const float* __restrict__ b2t,
                                              const float* __restrict__ st,
                                              u16* __restrict__ x2, int cb) {
    size_t i4 = (size_t)blockIdx.x * 256 + threadIdx.x;
    int bl = (int)(i4 / (CHW / 4));
    int b = cb + bl;
    size_t off4 = i4 % (CHW / 4);
    float mean = st[32 + 2 * b] * (1.0f / CHW);
    float var  = st[32 + 2 * b + 1] * (1.0f / CHW) - mean * mean;
    float rstd = rsqrtf(var + LNEPS);
    float4 v  = ((const float4*)(r + (size_t)bl * CHW))[off4];
    float4 wv = ((const float4*)w2t)[off4];
    float4 bv = ((const float4*)b2t)[off4];
    uint2 o; u16* op = (u16*)&o;
    op[0] = f2bf((v.x - mean) * rstd * wv.x + bv.x);
    op[1] = f2bf((v.y - mean) * rstd * wv.y + bv.y);
    op[2] = f2bf((v.z - mean) * rstd * wv.z + bv.z);
    op[3] = f2bf((v.w - mean) * rstd * wv.w + bv.w);
    ((uint2*)(x2 + (size_t)bl * CHW))[off4] = o;
}

// ---------- out[c][p] = x2[p][c] + ffOut[p][c] (transpose back) ----------
__global__ __launch_bounds__(256) void final_t_k(const u16* __restrict__ x2,
                                                 const float* __restrict__ ffo,
                                                 float* __restrict__ out, int cb) {
    int c0 = blockIdx.x * 32, p0 = blockIdx.y * 32, bl = blockIdx.z;
    int b = cb + bl;
    __shared__ float T[32][33];
    int tx = threadIdx.x & 31, ty = threadIdx.x >> 5;
#pragma unroll
    for (int i = 0; i < 4; ++i) {
        size_t o = (size_t)bl * CHW + (size_t)(p0 + ty + i * 8) * CCH + c0 + tx;
        T[ty + i * 8][tx] = ffo[o] + bf2f(x2[o]);   // T[p_local][c_local]
    }
    __syncthreads();
    float* ob = out + (size_t)b * CHW;
#pragma unroll
    for (int i = 0; i < 4; ++i)
        ob[(size_t)(c0 + ty + i * 8) * HWS + p0 + tx] = T[tx][ty + i * 8];
}

extern "C" void kernel_launch(void* const* d_in, const int* in_sizes, int n_in,
                              void* d_out, int out_size, void* d_ws, size_t ws_size,
                              hipStream_t stream) {
    const float* x    = (const float*)d_in[0];
    const float* ln1w = (const float*)d_in[1];
    const float* ln1b = (const float*)d_in[2];
    const float* qw   = (const float*)d_in[3];
    const float* qb   = (const float*)d_in[4];
    const float* kw   = (const float*)d_in[5];
    const float* kb   = (const float*)d_in[6];
    const float* vw   = (const float*)d_in[7];
    const float* vb   = (const float*)d_in[8];
    const float* huw  = (const float*)d_in[9];
    const float* hub  = (const float*)d_in[10];
    const float* ln2w = (const float*)d_in[11];
    const float* ln2b = (const float*)d_in[12];
    const float* f1w  = (const float*)d_in[13];
    const float* f1b  = (const float*)d_in[14];
    const float* f2w  = (const float*)d_in[15];
    const float* f2b  = (const float*)d_in[16];
    float* out = (float*)d_out;
    float* ws = (float*)d_ws;

    // fixed ws region (floats)
    float* stats = ws;                      // 64
    float* qkvb  = ws + 64;                 // 1536
    u16*   wqkv  = (u16*)(ws + 1600);       // 1536x512 bf16 -> 393216 f
    u16*   whu   = (u16*)(ws + 394816);     // 512x512        -> 131072 f
    u16*   wf1   = (u16*)(ws + 525888);     // 2048x512       -> 524288 f
    u16*   wf2   = (u16*)(ws + 1050176);    // 512x2048       -> 524288 f
    float* w2t   = ws + 1574464;            // 2097152 f
    float* b2t   = ws + 3671616;            // 2097152 f
    float* pstat = ws + 5768768;            // 16*2048*2 = 65536 f (LN2 partials)
    float* kpart = ws + 5834304;            // 16*16*512*2 = 262144 f (K col partials)
    float* kstat = ws + 6096448;            // 16*512*2 = 16384 f (K col m,inv)
    float* kvbuf = ws + 6112832;            // G*32768 f

    // chunk size G: fixed(6112832) + G*32768 + region 3.5*G*2097152
    int G = 16;
    while (G > 1 && (6112832ull + (size_t)G * 7372800ull) * 4ull > ws_size) G >>= 1;
    const int nch = BATCH / G;
    const size_t U = (size_t)G * CHW;       // chunk elems (== floats for fp32 bufs)

    float* R       = kvbuf + (size_t)G * 32768;
    u16*   a_bf    = (u16*)R;               // CHWg bf16 (also attnRaw)
    u16*   QKVb    = (u16*)(R + U / 2);     // 3*CHWg bf16
    float* attnOut = R + U / 2;             // CHWg f32 (overlays QKV after attn)
    float* rbuf    = R + 3 * U / 2;         // CHWg f32
    u16*   x2bf    = (u16*)R;               // CHWg bf16 (overlays attnRaw)
    u16*   Hbuf    = (u16*)(R + U / 2);     // 4*CHWg bf16 (overlays attnOut,r)
    float* ffOut   = R + 5 * U / 2;         // CHWg f32

    hipMemsetAsync(stats, 0, 64 * sizeof(float), stream);

    // weight conversions (every call; inputs restored by harness each iter)
    cvt_k<<<dim3(256), 256, 0, stream>>>(qw, wqkv, 65536);
    cvt_k<<<dim3(256), 256, 0, stream>>>(kw, wqkv + 262144, 65536);
    cvt_k<<<dim3(256), 256, 0, stream>>>(vw, wqkv + 524288, 65536);
    cvt_k<<<dim3(256), 256, 0, stream>>>(huw, whu, 65536);
    cvt_k<<<dim3(1024), 256, 0, stream>>>(f1w, wf1, 262144);
    cvt_k<<<dim3(1024), 256, 0, stream>>>(f2w, wf2, 262144);
    tr_k<<<dim3(128, 16), 256, 0, stream>>>(ln2w, w2t);
    tr_k<<<dim3(128, 16), 256, 0, stream>>>(ln2b, b2t);
    hipMemcpyAsync(qkvb,        qb, 512 * sizeof(float), hipMemcpyDeviceToDevice, stream);
    hipMemcpyAsync(qkvb + 512,  kb, 512 * sizeof(float), hipMemcpyDeviceToDevice, stream);
    hipMemcpyAsync(qkvb + 1024, vb, 512 * sizeof(float), hipMemcpyDeviceToDevice, stream);

    stats_k<<<dim3(64, BATCH), 256, 0, stream>>>(x, stats);

    for (int g = 0; g < nch; ++g) {
        const int cb = g * G;
        const int mt = G * 32;   // m-tiles (M = G*4096)
        // LN1 + transpose + cvt -> a[p][c] bf16
        ln1t_k<<<dim3(128, 16, G), 256, 0, stream>>>(x, ln1w, ln1b, stats, a_bf, cb);
        // fused QKV GEMM: [G*4096 x 512] x [1536 x 512]^T -> bf16 [m][1536]
        gemm_tn<512, 0, 1><<<dim3(mt * 12), 256, 0, stream>>>(a_bf, wqkv, qkvb, QKVb, QKVLD, 12);
        softmax_row_k<<<dim3(G * 1024), 256, 0, stream>>>(QKVb);
        // K column softmax stats (normalization fused into kv_k2)
        kcolstat_k<<<dim3(16, G), 256, 0, stream>>>(QKVb, kpart);
        kcolmerge_k<<<dim3(G), 256, 0, stream>>>(kpart, kstat);
        hipMemsetAsync(kvbuf, 0, (size_t)G * 32768 * sizeof(float), stream);
        kv_k2<<<dim3(16, NHEAD, G), 256, 0, stream>>>(QKVb, kstat, kvbuf);
        attn_k2<<<dim3(64, NHEAD, G), 256, 0, stream>>>(QKVb, kvbuf, a_bf);  // attnRaw over a
        // hu GEMM -> attnOut fp32 [m][512]
        gemm_tn<512, 0, 0><<<dim3(mt * 4), 256, 0, stream>>>(a_bf, whu, hub, attnOut, CCH, 4);
        resid_t_k<<<dim3(128, 16, G), 256, 0, stream>>>(x, attnOut, rbuf, pstat, cb);
        red2_k<<<dim3(G), 256, 0, stream>>>(pstat, stats, cb);
        ln2a_k<<<dim3(G * 2048), 256, 0, stream>>>(rbuf, w2t, b2t, stats, x2bf, cb);
        // ff1 GEMM + gelu -> H bf16 [m][2048]
        gemm_tn<512, 1, 1><<<dim3(mt * 16), 256, 0, stream>>>(x2bf, wf1, f1b, Hbuf, DHFF, 16);
        // ff2 GEMM -> ffOut fp32 [m][512]
        gemm_tn<2048, 0, 0><<<dim3(mt * 4), 256, 0, stream>>>(Hbuf, wf2, f2b, ffOut, CCH, 4);
        // out[c][p] = x2 + ff
        final_t_k<<<dim3(16, 128, G), 256, 0, stream>>>(x2bf, ffOut, out, cb);
    }
}

// Round 8
// 1450.590 us; speedup vs baseline: 1.1931x; 1.0338x over previous
//
#include <hip/hip_runtime.h>
#include <math.h>

#define BATCH 16
#define CCH   512
#define HWS   4096                 // H*W
#define CHW   (CCH*HWS)            // per-batch elements: 2,097,152
#define DHFF  2048
#define NHEAD 8
#define HD    64
#define QKVLD 1536
#define LNEPS 1e-5f

typedef unsigned short u16;
typedef __bf16 bf16x8 __attribute__((ext_vector_type(8)));
typedef float f32x4 __attribute__((ext_vector_type(4)));

// tanh-form GELU via sigmoid identity: 0.5x(1+tanh(y)) = x*sigmoid(2y).
__device__ __forceinline__ float gelu_f(float x) {
    float y = 1.5957691216057308f * x * (1.0f + 0.044715f * x * x);
    return x / (1.0f + __expf(-y));
}
__device__ __forceinline__ u16 f2bf(float f) {
    union { float f; unsigned u; } c; c.f = f;
    unsigned r = c.u + 0x7FFFu + ((c.u >> 16) & 1u);
    return (u16)(r >> 16);
}
__device__ __forceinline__ float bf2f(u16 h) {
    union { unsigned u; float f; } c; c.u = ((unsigned)h) << 16; return c.f;
}
// native packed bf16 convert (compiler emits v_cvt_pk_bf16_f32, RNE)
__device__ __forceinline__ uint2 pack_bf16x4(float v0, float v1, float v2, float v3) {
    union { uint2 u; __bf16 b[4]; } o;
    o.b[0] = (__bf16)v0; o.b[1] = (__bf16)v1; o.b[2] = (__bf16)v2; o.b[3] = (__bf16)v3;
    return o.u;
}
// direct global->LDS 16B copy; lds base must be wave-uniform (HW: base + lane*16)
__device__ __forceinline__ void gld16(const u16* g, u16* l) {
    __builtin_amdgcn_global_load_lds((const __attribute__((address_space(1))) unsigned*)g,
                                     (__attribute__((address_space(3))) unsigned*)l, 16, 0, 0);
}

// ---------- shared GEMM core: 128x128 tile, BK=32, 4 waves, static dbuf ----------
// (r6-proven structure: issue STAGE(next) first, ds_read cur, MFMA, one barrier)
template<int K>
__device__ __forceinline__ void gemm_core(const u16* __restrict__ A,
                                          const u16* __restrict__ B,
                                          int m0, int n0,
                                          u16 (&As)[2][128 * 32],
                                          u16 (&Bs)[2][128 * 32],
                                          f32x4 (&acc)[4][4]) {
    const int tid = threadIdx.x;
    const int lane = tid & 63;
    const int w = tid >> 6;
    const int wm = (w & 1) * 64, wn = (w >> 1) * 64;
    const int ls = lane & 15, lq = lane >> 4;
#pragma unroll
    for (int i = 0; i < 4; ++i)
#pragma unroll
        for (int j = 0; j < 4; ++j) acc[i][j] = (f32x4){0.f, 0.f, 0.f, 0.f};

    const int srow = w * 16 + (lane >> 2);
    const int scol = (lane & 3) * 8;
    const u16* gA0 = A + (size_t)(m0 + srow) * K + scol;
    const u16* gA1 = gA0 + (size_t)64 * K;
    const u16* gB0 = B + (size_t)(n0 + srow) * K + scol;
    const u16* gB1 = gB0 + (size_t)64 * K;
    const int lo = w * 512;

    gld16(gA0, &As[0][lo]);
    gld16(gA1, &As[0][2048 + lo]);
    gld16(gB0, &Bs[0][lo]);
    gld16(gB1, &Bs[0][2048 + lo]);
    __syncthreads();

#pragma unroll 8
    for (int kt = 0; kt < K; kt += 32) {
        const int cur = (kt >> 5) & 1;          // compile-time under even unroll
        const int nx = cur ^ 1;
        if (kt + 32 < K) {
            gld16(gA0 + kt + 32, &As[nx][lo]);
            gld16(gA1 + kt + 32, &As[nx][2048 + lo]);
            gld16(gB0 + kt + 32, &Bs[nx][lo]);
            gld16(gB1 + kt + 32, &Bs[nx][2048 + lo]);
        }
        bf16x8 af[4], bfv[4];
#pragma unroll
        for (int i = 0; i < 4; ++i)
            af[i] = *(bf16x8*)&As[cur][(wm + i * 16 + ls) * 32 + lq * 8];
#pragma unroll
        for (int j = 0; j < 4; ++j)
            bfv[j] = *(bf16x8*)&Bs[cur][(wn + j * 16 + ls) * 32 + lq * 8];
#pragma unroll
        for (int i = 0; i < 4; ++i)
#pragma unroll
            for (int j = 0; j < 4; ++j)
                acc[i][j] = __builtin_amdgcn_mfma_f32_16x16x32_bf16(bfv[j], af[i], acc[i][j], 0, 0, 0);
        if (kt + 32 < K)
            __syncthreads();
    }
}

// ---------- per-batch sum/sumsq over x (LN1 stats) ----------
__global__ __launch_bounds__(256) void stats_k(const float* __restrict__ src,
                                               float* __restrict__ st) {
    int b = blockIdx.y;
    const float4* p = (const float4*)(src + (size_t)b * CHW + (size_t)blockIdx.x * (CHW / 64));
    float s = 0.f, ss = 0.f;
    for (int i = threadIdx.x; i < (CHW / 64 / 4); i += 256) {
        float4 v = p[i];
        s  += v.x + v.y + v.z + v.w;
        ss += v.x * v.x + v.y * v.y + v.z * v.z + v.w * v.w;
    }
    __shared__ float r1[256], r2[256];
    int t = threadIdx.x;
    r1[t] = s; r2[t] = ss; __syncthreads();
    for (int o = 128; o > 0; o >>= 1) {
        if (t < o) { r1[t] += r1[t + o]; r2[t] += r2[t + o]; }
        __syncthreads();
    }
    if (t == 0) { atomicAdd(&st[2 * b], r1[0]); atomicAdd(&st[2 * b + 1], r2[0]); }
}

// ---------- fp32 -> bf16 flat convert (weights) ----------
__global__ __launch_bounds__(256) void cvt_k(const float* __restrict__ src,
                                             u16* __restrict__ dst, int n4) {
    int i = blockIdx.x * 256 + threadIdx.x;
    if (i >= n4) return;
    float4 v = ((const float4*)src)[i];
    ((uint2*)dst)[i] = pack_bf16x4(v.x, v.y, v.z, v.w);
}

// ---------- fp32 [c][p] -> fp32 [p][c] transpose (ln2 w/b) ----------
__global__ __launch_bounds__(256) void tr_k(const float* __restrict__ src,
                                            float* __restrict__ dst) {
    int p0 = blockIdx.x * 32, c0 = blockIdx.y * 32;
    __shared__ float T[32][33];
    int tx = threadIdx.x & 31, ty = threadIdx.x >> 5;
#pragma unroll
    for (int i = 0; i < 4; ++i)
        T[ty + i * 8][tx] = src[(size_t)(c0 + ty + i * 8) * HWS + p0 + tx];
    __syncthreads();
#pragma unroll
    for (int i = 0; i < 4; ++i)
        dst[(size_t)(p0 + ty + i * 8) * CCH + c0 + tx] = T[tx][ty + i * 8];
}

// ---------- LN1 + transpose + cvt: a[p][c] bf16 = LN1(x)[c][p] ----------
__global__ __launch_bounds__(256) void ln1t_k(const float* __restrict__ x,
                                              const float* __restrict__ w,
                                              const float* __restrict__ bb,
                                              const float* __restrict__ st,
                                              u16* __restrict__ a, int cb) {
    int p0 = blockIdx.x * 32, c0 = blockIdx.y * 32, bl = blockIdx.z;
    int b = cb + bl;
    float mean = st[2 * b] * (1.0f / CHW);
    float var  = st[2 * b + 1] * (1.0f / CHW) - mean * mean;
    float rstd = rsqrtf(var + LNEPS);
    __shared__ float T[32][33];
    int tx = threadIdx.x & 31, ty = threadIdx.x >> 5;
    const float* xb = x + (size_t)b * CHW;
#pragma unroll
    for (int i = 0; i < 4; ++i) {
        size_t o = (size_t)(c0 + ty + i * 8) * HWS + p0 + tx;
        T[ty + i * 8][tx] = (xb[o] - mean) * rstd * w[o] + bb[o];
    }
    __syncthreads();
    u16* ab = a + (size_t)bl * CHW;
#pragma unroll
    for (int i = 0; i < 4; ++i)
        ab[(size_t)(p0 + ty + i * 8) * CCH + c0 + tx] = f2bf(T[tx][ty + i * 8]);
}

// ---------- plain GEMM (QKV, ff1): Out[m][n] bf16 = A@B^T + bias, opt gelu ----------
template<int K, int ACT>
__global__ __launch_bounds__(256) void gemm_tn(const u16* __restrict__ A,
                                               const u16* __restrict__ B,
                                               const float* __restrict__ bias,
                                               u16* __restrict__ Out,
                                               int ldo, int nt) {
    __shared__ u16 As[2][128 * 32];
    __shared__ u16 Bs[2][128 * 32];
    const int cpx = gridDim.x >> 3;
    const int wg = ((int)blockIdx.x & 7) * cpx + ((int)blockIdx.x >> 3);
    const int m0 = (wg / nt) * 128;
    const int n0 = (wg % nt) * 128;
    f32x4 acc[4][4];
    gemm_core<K>(A, B, m0, n0, As, Bs, acc);

    const int lane = threadIdx.x & 63;
    const int w = threadIdx.x >> 6;
    const int wm = (w & 1) * 64, wn = (w >> 1) * 64;
    const int ls = lane & 15, lq = lane >> 4;
#pragma unroll
    for (int j = 0; j < 4; ++j) {
        int nb = n0 + wn + j * 16 + lq * 4;
        float4 bv = *(const float4*)&bias[nb];
#pragma unroll
        for (int i = 0; i < 4; ++i) {
            int m = m0 + wm + i * 16 + ls;
            float v0 = acc[i][j][0] + bv.x;
            float v1 = acc[i][j][1] + bv.y;
            float v2 = acc[i][j][2] + bv.z;
            float v3 = acc[i][j][3] + bv.w;
            if (ACT) { v0 = gelu_f(v0); v1 = gelu_f(v1); v2 = gelu_f(v2); v3 = gelu_f(v3); }
            *(uint2*)(Out + (size_t)m * ldo + nb) = pack_bf16x4(v0, v1, v2, v3);
        }
    }
}

// ---------- hu GEMM fused with residual + LN2 partial stats ----------
// r[p][c] = x[c][p] + (attnRaw @ huw^T + hub)[p][c]; per-block (sum,sumsq) -> pstat
__global__ __launch_bounds__(256) void gemm_hu_resid(const u16* __restrict__ A,
                                                     const u16* __restrict__ B,
                                                     const float* __restrict__ bias,
                                                     float* __restrict__ r,
                                                     const float* __restrict__ x,
                                                     float* __restrict__ pstat, int cb) {
    __shared__ u16 As[2][128 * 32];
    __shared__ u16 Bs[2][128 * 32];
    __shared__ float r1[256], r2[256];
    const int nt = 4;
    const int cpx = gridDim.x >> 3;
    const int wg = ((int)blockIdx.x & 7) * cpx + ((int)blockIdx.x >> 3);
    const int m0 = (wg / nt) * 128;
    const int n0 = (wg % nt) * 128;
    f32x4 acc[4][4];
    gemm_core<512>(A, B, m0, n0, As, Bs, acc);

    const int lane = threadIdx.x & 63;
    const int w = threadIdx.x >> 6;
    const int wm = (w & 1) * 64, wn = (w >> 1) * 64;
    const int ls = lane & 15, lq = lane >> 4;
    const int bl = m0 >> 12;             // batch within chunk (m0/4096)
    const int p0loc = m0 & 4095;
    const float* xb = x + (size_t)(cb + bl) * CHW;
    float* rb = r + (size_t)bl * CHW;
    float s = 0.f, ss = 0.f;
#pragma unroll
    for (int j = 0; j < 4; ++j) {
        int nb = n0 + wn + j * 16 + lq * 4;  // channel c base
        float4 bv = *(const float4*)&bias[nb];
#pragma unroll
        for (int i = 0; i < 4; ++i) {
            int p = p0loc + wm + i * 16 + ls;
            float v0 = acc[i][j][0] + bv.x + xb[(size_t)(nb + 0) * HWS + p];
            float v1 = acc[i][j][1] + bv.y + xb[(size_t)(nb + 1) * HWS + p];
            float v2 = acc[i][j][2] + bv.z + xb[(size_t)(nb + 2) * HWS + p];
            float v3 = acc[i][j][3] + bv.w + xb[(size_t)(nb + 3) * HWS + p];
            *(float4*)(rb + (size_t)p * CCH + nb) = (float4){v0, v1, v2, v3};
            s  += v0 + v1 + v2 + v3;
            ss += v0 * v0 + v1 * v1 + v2 * v2 + v3 * v3;
        }
    }
    int t = threadIdx.x;
    __syncthreads();
    r1[t] = s; r2[t] = ss; __syncthreads();
    for (int o = 128; o > 0; o >>= 1) {
        if (t < o) { r1[t] += r1[t + o]; r2[t] += r2[t + o]; }
        __syncthreads();
    }
    if (t == 0) {
        int slot = ((p0loc >> 7) << 2) + (wg % nt);          // 0..127
        float* pp = pstat + ((size_t)(cb + bl) * 128 + slot) * 2;
        pp[0] = r1[0]; pp[1] = r2[0];
    }
}

// ---------- ff2 GEMM fused with final residual + transpose-out ----------
// out[c][p] = x2[p][c] + (H @ f2w^T + f2b)[p][c]; LDS-transposed coalesced store.
// Tt aliases the dead As/Bs storage via union -> 33.3 KB total LDS (was 66 KB).
__global__ __launch_bounds__(256) void gemm_ff2_final(const u16* __restrict__ A,
                                                      const u16* __restrict__ B,
                                                      const float* __restrict__ bias,
                                                      float* __restrict__ out,
                                                      const u16* __restrict__ x2,
                                                      int cb) {
    __shared__ union {
        struct { u16 As[2][128 * 32]; u16 Bs[2][128 * 32]; } g;
        float Tt[64][130];
    } shm;
    const int nt = 4;
    const int cpx = gridDim.x >> 3;
    const int wg = ((int)blockIdx.x & 7) * cpx + ((int)blockIdx.x >> 3);
    const int m0 = (wg / nt) * 128;
    const int n0 = (wg % nt) * 128;
    f32x4 acc[4][4];
    gemm_core<2048>(A, B, m0, n0, shm.g.As, shm.g.Bs, acc);

    const int tid = threadIdx.x;
    const int lane = tid & 63;
    const int w = tid >> 6;
    const int wm = (w & 1) * 64, wn = (w >> 1) * 64;
    const int ls = lane & 15, lq = lane >> 4;
    const int bl = m0 >> 12;
    const int p0loc = m0 & 4095;
    const u16* x2b = x2 + (size_t)bl * CHW;
    float* ob = out + (size_t)(cb + bl) * CHW;

    const int row = tid >> 2, mc = (tid & 3) * 32;
#pragma unroll
    for (int rnd = 0; rnd < 2; ++rnd) {
        __syncthreads();                 // orders As/Bs death (rnd0) / prev reads (rnd1) vs Tt writes
        if ((wn >> 6) == rnd) {
#pragma unroll
            for (int j = 0; j < 4; ++j) {
                int nloc = wn + j * 16 + lq * 4;             // 0..127 block-local c
                float4 bv = *(const float4*)&bias[n0 + nloc];
#pragma unroll
                for (int i = 0; i < 4; ++i) {
                    int m = wm + i * 16 + ls;                // block-local p
                    uint2 xr = *(const uint2*)&x2b[(size_t)(p0loc + m) * CCH + n0 + nloc];
                    u16* xp = (u16*)&xr;
                    int tr = nloc & 63;
                    shm.Tt[tr + 0][m] = acc[i][j][0] + bv.x + bf2f(xp[0]);
                    shm.Tt[tr + 1][m] = acc[i][j][1] + bv.y + bf2f(xp[1]);
                    shm.Tt[tr + 2][m] = acc[i][j][2] + bv.z + bf2f(xp[2]);
                    shm.Tt[tr + 3][m] = acc[i][j][3] + bv.w + bf2f(xp[3]);
                }
            }
        }
        __syncthreads();
        // all 256 threads: write 64 c-rows x 128 p coalesced
        float* orow = ob + (size_t)(n0 + rnd * 64 + row) * HWS + p0loc + mc;
#pragma unroll
        for (int q = 0; q < 32; q += 4)
            *(float4*)(orow + q) = *(float4*)&shm.Tt[row][mc + q];
    }
}

// ---------- softmax over Q channels (cols 0..511 of QKV rows), per pixel ----------
__global__ __launch_bounds__(256) void softmax_row_k(u16* __restrict__ QKV) {
    int m = blockIdx.x * 4 + (threadIdx.x >> 6);
    int lane = threadIdx.x & 63;
    u16* row = QKV + (size_t)m * QKVLD + lane * 8;
    uint4 raw = *(uint4*)row;
    u16* pr = (u16*)&raw;
    float v[8];
#pragma unroll
    for (int i = 0; i < 8; ++i) v[i] = bf2f(pr[i]);
    float mx = v[0];
#pragma unroll
    for (int i = 1; i < 8; ++i) mx = fmaxf(mx, v[i]);
    for (int o = 32; o > 0; o >>= 1) mx = fmaxf(mx, __shfl_xor(mx, o, 64));
    float s = 0.f;
#pragma unroll
    for (int i = 0; i < 8; ++i) { v[i] = __expf(v[i] - mx); s += v[i]; }
    for (int o = 32; o > 0; o >>= 1) s += __shfl_xor(s, o, 64);
    float inv = 1.0f / s;
#pragma unroll
    for (int i = 0; i < 8; ++i) pr[i] = f2bf(v[i] * inv);
    *(uint4*)row = raw;
}

// ---------- K-column softmax partial stats: per (b, 256-row chunk), per column ----------
__global__ __launch_bounds__(256) void kcolstat_k(const u16* __restrict__ QKV,
                                                  float* __restrict__ kpart) {
    int pc = blockIdx.x, bl = blockIdx.y;
    int cg = threadIdx.x & 63;           // column group (8 cols)
    int ps = threadIdx.x >> 6;           // p segment 0..3 (64 rows each)
    const u16* base = QKV + (size_t)bl * HWS * QKVLD + CCH + cg * 8;
    int p0 = pc * 256 + ps * 64;
    float m[8];
#pragma unroll
    for (int i = 0; i < 8; ++i) m[i] = -1e30f;
    for (int p = p0; p < p0 + 64; ++p) {
        uint4 r = *(const uint4*)(base + (size_t)p * QKVLD);
        u16* rp = (u16*)&r;
#pragma unroll
        for (int i = 0; i < 8; ++i) m[i] = fmaxf(m[i], bf2f(rp[i]));
    }
    __shared__ float red[4][512];
#pragma unroll
    for (int i = 0; i < 8; ++i) red[ps][cg * 8 + i] = m[i];
    __syncthreads();
#pragma unroll
    for (int i = 0; i < 8; ++i)
        m[i] = fmaxf(fmaxf(red[0][cg * 8 + i], red[1][cg * 8 + i]),
                     fmaxf(red[2][cg * 8 + i], red[3][cg * 8 + i]));
    __syncthreads();
    float s[8];
#pragma unroll
    for (int i = 0; i < 8; ++i) s[i] = 0.f;
    for (int p = p0; p < p0 + 64; ++p) {      // L2-hot second pass
        uint4 r = *(const uint4*)(base + (size_t)p * QKVLD);
        u16* rp = (u16*)&r;
#pragma unroll
        for (int i = 0; i < 8; ++i) s[i] += __expf(bf2f(rp[i]) - m[i]);
    }
#pragma unroll
    for (int i = 0; i < 8; ++i) red[ps][cg * 8 + i] = s[i];
    __syncthreads();
    if (ps == 0) {
        float* outp = kpart + (((size_t)bl * 16 + pc) * 512 + cg * 8) * 2;
#pragma unroll
        for (int i = 0; i < 8; ++i) {
            float sv = red[0][cg * 8 + i] + red[1][cg * 8 + i] +
                       red[2][cg * 8 + i] + red[3][cg * 8 + i];
            outp[2 * i] = m[i]; outp[2 * i + 1] = sv;
        }
    }
}

// ---------- merge 16 chunk partials -> (max, 1/sum) per column ----------
__global__ __launch_bounds__(256) void kcolmerge_k(const float* __restrict__ kpart,
                                                   float* __restrict__ kstat) {
    int bl = blockIdx.x;
#pragma unroll
    for (int j = 0; j < 2; ++j) {
        int col = threadIdx.x * 2 + j;
        float m = -1e30f;
        for (int pc = 0; pc < 16; ++pc)
            m = fmaxf(m, kpart[(((size_t)bl * 16 + pc) * 512 + col) * 2]);
        float s = 0.f;
        for (int pc = 0; pc < 16; ++pc) {
            const float* p = kpart + (((size_t)bl * 16 + pc) * 512 + col) * 2;
            s += p[1] * __expf(p[0] - m);
        }
        kstat[((size_t)bl * 512 + col) * 2]     = m;
        kstat[((size_t)bl * 512 + col) * 2 + 1] = 1.0f / s;
    }
}

// ---------- KV[b,h,k,v] = sum_p softmaxK[p][hk]*V[p][hv] (atomic over 16 p-chunks) ----------
__global__ __launch_bounds__(256) void kv_k2(const u16* __restrict__ QKV,
                                             const float* __restrict__ kstat,
                                             float* __restrict__ KV) {
    int pc = blockIdx.x, h = blockIdx.y, bl = blockIdx.z;
    const u16* kbase = QKV + (size_t)bl * HWS * QKVLD + CCH + h * HD;
    const u16* vbase = kbase + CCH;
    float* kvb = KV + ((size_t)bl * NHEAD + h) * (HD * HD);
    __shared__ float Ks[64][65], Vs[64][65];
    __shared__ float Ms[64], Is[64];
    int tid = threadIdx.x;
    if (tid < 64) {
        const float* sp = kstat + ((size_t)bl * 512 + h * HD + tid) * 2;
        Ms[tid] = sp[0]; Is[tid] = sp[1];
    }
    int tk = tid >> 4, tv = tid & 15;
    float acc[4][4];
#pragma unroll
    for (int i = 0; i < 4; ++i)
#pragma unroll
        for (int j = 0; j < 4; ++j) acc[i][j] = 0.f;

    for (int s = 0; s < 4; ++s) {
        int pbase = pc * 256 + s * 64;
        __syncthreads();
#pragma unroll
        for (int j = 0; j < 2; ++j) {
            int li = tid + j * 256;
            int pl = li >> 3, c8 = (li & 7) * 8;
            uint4 kr = *(const uint4*)(kbase + (size_t)(pbase + pl) * QKVLD + c8);
            uint4 vr = *(const uint4*)(vbase + (size_t)(pbase + pl) * QKVLD + c8);
            u16* kp = (u16*)&kr; u16* vp = (u16*)&vr;
#pragma unroll
            for (int t = 0; t < 8; ++t) {
                Ks[pl][c8 + t] = __expf(bf2f(kp[t]) - Ms[c8 + t]) * Is[c8 + t];
                Vs[pl][c8 + t] = bf2f(vp[t]);
            }
        }
        __syncthreads();
#pragma unroll 4
        for (int p = 0; p < 64; ++p) {
            float ka[4], va[4];
#pragma unroll
            for (int i = 0; i < 4; ++i) { ka[i] = Ks[p][tk * 4 + i]; va[i] = Vs[p][tv * 4 + i]; }
#pragma unroll
            for (int i = 0; i < 4; ++i)
#pragma unroll
                for (int j = 0; j < 4; ++j) acc[i][j] += ka[i] * va[j];
        }
    }
#pragma unroll
    for (int i = 0; i < 4; ++i)
#pragma unroll
        for (int j = 0; j < 4; ++j)
            atomicAdd(&kvb[(size_t)(tk * 4 + i) * HD + tv * 4 + j], acc[i][j]);
}

// ---------- attnRaw[p][hv] bf16 = sum_k KV[k][v]*Q[p][hk] ----------
__global__ __launch_bounds__(256) void attn_k2(const u16* __restrict__ QKV,
                                               const float* __restrict__ KV,
                                               u16* __restrict__ attnRaw) {
    int pt = blockIdx.x, h = blockIdx.y, bl = blockIdx.z;
    const u16* qbase = QKV + (size_t)bl * HWS * QKVLD + h * HD;
    const float* kvb = KV + ((size_t)bl * NHEAD + h) * (HD * HD);
    __shared__ float KVs[64][68], Qs[64][68];
    int tid = threadIdx.x;
#pragma unroll
    for (int j = 0; j < 4; ++j) {
        int li = tid + j * 256;
        int k = li >> 4, c4 = (li & 15) * 4;
        *(float4*)&KVs[k][c4] = *(const float4*)(kvb + (size_t)k * HD + c4);
    }
#pragma unroll
    for (int j = 0; j < 2; ++j) {
        int li = tid + j * 256;
        int pl = li >> 3, c8 = (li & 7) * 8;
        uint4 qr = *(const uint4*)(qbase + (size_t)(pt * 64 + pl) * QKVLD + c8);
        u16* qp = (u16*)&qr;
#pragma unroll
        for (int t = 0; t < 8; ++t) Qs[pl][c8 + t] = bf2f(qp[t]);
    }
    __syncthreads();
    int tp = tid >> 4, tv = tid & 15;
    float acc[4][4];
#pragma unroll
    for (int i = 0; i < 4; ++i)
#pragma unroll
        for (int j = 0; j < 4; ++j) acc[i][j] = 0.f;
#pragma unroll 4
    for (int k = 0; k < 64; ++k) {
        float qa[4], kv4[4];
#pragma unroll
        for (int i = 0; i < 4; ++i) { qa[i] = Qs[tp * 4 + i][k]; kv4[i] = KVs[k][tv * 4 + i]; }
#pragma unroll
        for (int i = 0; i < 4; ++i)
#pragma unroll
            for (int j = 0; j < 4; ++j) acc[i][j] += qa[i] * kv4[j];
    }
#pragma unroll
    for (int i = 0; i < 4; ++i) {
        *(uint2*)(attnRaw + (size_t)(bl * HWS + pt * 64 + tp * 4 + i) * CCH + h * HD + tv * 4) =
            pack_bf16x4(acc[i][0], acc[i][1], acc[i][2], acc[i][3]);
    }
}

// ---------- reduce 128 per-block partials -> LN2 stats ----------
__global__ __launch_bounds__(128) void red2_k(const float* __restrict__ pstat,
                                              float* __restrict__ st, int cb) {
    int b = cb + blockIdx.x;
    const float* p = pstat + (size_t)b * 256;
    int t = threadIdx.x;
    float s = p[2 * t], ss = p[2 * t + 1];
    for (int o = 32; o > 0; o >>= 1) { s += __shfl_down(s, o, 64); ss += __shfl_down(ss, o, 64); }
    __shared__ float sh[4];
    if ((t & 63) == 0) { sh[(t >> 6) * 2] = s; sh[(t >> 6) * 2 + 1] = ss; }
    __syncthreads();
    if (t == 0) { st[32 + 2 * b] = sh[0] + sh[2]; st[32 + 2 * b + 1] = sh[1] + sh[3]; }
}

// ---------- x2 bf16 [p][c] = LN2(r) ----------
__global__ __launch_bounds__(256) void ln2a_k(const float* __restrict__ r,
                                              const float* __restrict__ w2t,
                                              const float* __restrict__ b2t,
                                              const float* __restrict__ st,
                                              u16* __restrict__ x2, int cb) {
    size_t i4 = (size_t)blockIdx.x * 256 + threadIdx.x;
    int bl = (int)(i4 / (CHW / 4));
    int b = cb + bl;
    size_t off4 = i4 % (CHW / 4);
    float mean = st[32 + 2 * b] * (1.0f / CHW);
    float var  = st[32 + 2 * b + 1] * (1.0f / CHW) - mean * mean;
    float rstd = rsqrtf(var + LNEPS);
    float4 v  = ((const float4*)(r + (size_t)bl * CHW))[off4];
    float4 wv = ((const float4*)w2t)[off4];
    float4 bv = ((const float4*)b2t)[off4];
    ((uint2*)(x2 + (size_t)bl * CHW))[off4] =
        pack_bf16x4((v.x - mean) * rstd * wv.x + bv.x,
                    (v.y - mean) * rstd * wv.y + bv.y,
                    (v.z - mean) * rstd * wv.z + bv.z,
                    (v.w - mean) * rstd * wv.w + bv.w);
}

extern "C" void kernel_launch(void* const* d_in, const int* in_sizes, int n_in,
                              void* d_out, int out_size, void* d_ws, size_t ws_size,
                              hipStream_t stream) {
    const float* x    = (const float*)d_in[0];
    const float* ln1w = (const float*)d_in[1];
    const float* ln1b = (const float*)d_in[2];
    const float* qw   = (const float*)d_in[3];
    const float* qb   = (const float*)d_in[4];
    const float* kw   = (const float*)d_in[5];
    const float* kb   = (const float*)d_in[6];
    const float* vw   = (const float*)d_in[7];
    const float* vb   = (const float*)d_in[8];
    const float* huw  = (const float*)d_in[9];
    const float* hub  = (const float*)d_in[10];
    const float* ln2w = (const float*)d_in[11];
    const float* ln2b = (const float*)d_in[12];
    const float* f1w  = (const float*)d_in[13];
    const float* f1b  = (const float*)d_in[14];
    const float* f2w  = (const float*)d_in[15];
    const float* f2b  = (const float*)d_in[16];
    float* out = (float*)d_out;
    float* ws = (float*)d_ws;

    // fixed ws region (floats)
    float* stats = ws;                      // 64
    float* qkvb  = ws + 64;                 // 1536
    u16*   wqkv  = (u16*)(ws + 1600);       // 1536x512 bf16 -> 393216 f
    u16*   whu   = (u16*)(ws + 394816);     // 512x512        -> 131072 f
    u16*   wf1   = (u16*)(ws + 525888);     // 2048x512       -> 524288 f
    u16*   wf2   = (u16*)(ws + 1050176);    // 512x2048       -> 524288 f
    float* w2t   = ws + 1574464;            // 2097152 f
    float* b2t   = ws + 3671616;            // 2097152 f
    float* pstat = ws + 5768768;            // 16*128*2 = 4096 f (LN2 partials)
    float* kpart = ws + 5834304;            // 16*16*512*2 = 262144 f (K col partials)
    float* kstat = ws + 6096448;            // 16*512*2 = 16384 f (K col m,inv)
    float* kvbuf = ws + 6112832;            // G*32768 f

    // chunk size G: fixed + G*(32768 + 2.5*CHW) floats
    int G = 16;
    while (G > 1 && (6112832ull + (size_t)G * 5275648ull) * 4ull > ws_size) G >>= 1;
    const int nch = BATCH / G;
    const size_t U = (size_t)G * CHW;       // chunk elems

    float* R       = kvbuf + (size_t)G * 32768;
    u16*   a_bf    = (u16*)R;               // CHWg bf16 (attnRaw; later x2bf)
    u16*   QKVb    = (u16*)(R + U / 2);     // 3*CHWg bf16
    float* rbuf    = R + 3 * U / 2;         // CHWg f32
    u16*   x2bf    = (u16*)R;               // CHWg bf16 (overlays a_bf)
    u16*   Hbuf    = (u16*)(R + U / 2);     // 4*CHWg bf16 (overlays QKVb; tail overlays rbuf after its death)

    hipMemsetAsync(stats, 0, 64 * sizeof(float), stream);

    // weight conversions (every call; inputs restored by harness each iter)
    cvt_k<<<dim3(256), 256, 0, stream>>>(qw, wqkv, 65536);
    cvt_k<<<dim3(256), 256, 0, stream>>>(kw, wqkv + 262144, 65536);
    cvt_k<<<dim3(256), 256, 0, stream>>>(vw, wqkv + 524288, 65536);
    cvt_k<<<dim3(256), 256, 0, stream>>>(huw, whu, 65536);
    cvt_k<<<dim3(1024), 256, 0, stream>>>(f1w, wf1, 262144);
    cvt_k<<<dim3(1024), 256, 0, stream>>>(f2w, wf2, 262144);
    tr_k<<<dim3(128, 16), 256, 0, stream>>>(ln2w, w2t);
    tr_k<<<dim3(128, 16), 256, 0, stream>>>(ln2b, b2t);
    hipMemcpyAsync(qkvb,        qb, 512 * sizeof(float), hipMemcpyDeviceToDevice, stream);
    hipMemcpyAsync(qkvb + 512,  kb, 512 * sizeof(float), hipMemcpyDeviceToDevice, stream);
    hipMemcpyAsync(qkvb + 1024, vb, 512 * sizeof(float), hipMemcpyDeviceToDevice, stream);

    stats_k<<<dim3(64, BATCH), 256, 0, stream>>>(x, stats);

    for (int g = 0; g < nch; ++g) {
        const int cb = g * G;
        const int mt = G * 32;   // m-tiles (M = G*4096)
        // LN1 + transpose + cvt -> a[p][c] bf16
        ln1t_k<<<dim3(128, 16, G), 256, 0, stream>>>(x, ln1w, ln1b, stats, a_bf, cb);
        // fused QKV GEMM: [G*4096 x 512] x [1536 x 512]^T -> bf16 [m][1536]
        gemm_tn<512, 0><<<dim3(mt * 12), 256, 0, stream>>>(a_bf, wqkv, qkvb, QKVb, QKVLD, 12);
        softmax_row_k<<<dim3(G * 1024), 256, 0, stream>>>(QKVb);
        // K column softmax stats (normalization fused into kv_k2)
        kcolstat_k<<<dim3(16, G), 256, 0, stream>>>(QKVb, kpart);
        kcolmerge_k<<<dim3(G), 256, 0, stream>>>(kpart, kstat);
        hipMemsetAsync(kvbuf, 0, (size_t)G * 32768 * sizeof(float), stream);
        kv_k2<<<dim3(16, NHEAD, G), 256, 0, stream>>>(QKVb, kstat, kvbuf);
        attn_k2<<<dim3(64, NHEAD, G), 256, 0, stream>>>(QKVb, kvbuf, a_bf);  // attnRaw over a
        // hu GEMM fused with residual + LN2 stats -> rbuf
        gemm_hu_resid<<<dim3(mt * 4), 256, 0, stream>>>(a_bf, whu, hub, rbuf, x, pstat, cb);
        red2_k<<<dim3(G), 128, 0, stream>>>(pstat, stats, cb);
        ln2a_k<<<dim3(G * 2048), 256, 0, stream>>>(rbuf, w2t, b2t, stats, x2bf, cb);
        // ff1 GEMM + gelu -> H bf16 [m][2048]
        gemm_tn<512, 1><<<dim3(mt * 16), 256, 0, stream>>>(x2bf, wf1, f1b, Hbuf, DHFF, 16);
        // ff2 GEMM fused with final residual + transpose -> out
        gemm_ff2_final<<<dim3(mt * 4), 256, 0, stream>>>(Hbuf, wf2, f2b, out, x2bf, cb);
    }
}

// Round 9
// 1386.640 us; speedup vs baseline: 1.2481x; 1.0461x over previous
//
#include <hip/hip_runtime.h>
#include <math.h>

#define BATCH 16
#define CCH   512
#define HWS   4096                 // H*W
#define CHW   (CCH*HWS)            // per-batch elements: 2,097,152
#define DHFF  2048
#define NHEAD 8
#define HD    64
#define QKVLD 1536
#define LNEPS 1e-5f

typedef unsigned short u16;
typedef __bf16 bf16x8 __attribute__((ext_vector_type(8)));
typedef float f32x4 __attribute__((ext_vector_type(4)));

// tanh-form GELU via sigmoid identity: 0.5x(1+tanh(y)) = x*sigmoid(2y).
__device__ __forceinline__ float gelu_f(float x) {
    float y = 1.5957691216057308f * x * (1.0f + 0.044715f * x * x);
    return x / (1.0f + __expf(-y));
}
__device__ __forceinline__ u16 f2bf(float f) {
    union { float f; unsigned u; } c; c.f = f;
    unsigned r = c.u + 0x7FFFu + ((c.u >> 16) & 1u);
    return (u16)(r >> 16);
}
__device__ __forceinline__ float bf2f(u16 h) {
    union { unsigned u; float f; } c; c.u = ((unsigned)h) << 16; return c.f;
}
// native packed bf16 convert (compiler emits v_cvt_pk_bf16_f32, RNE)
__device__ __forceinline__ uint2 pack_bf16x4(float v0, float v1, float v2, float v3) {
    union { uint2 u; __bf16 b[4]; } o;
    o.b[0] = (__bf16)v0; o.b[1] = (__bf16)v1; o.b[2] = (__bf16)v2; o.b[3] = (__bf16)v3;
    return o.u;
}
// direct global->LDS 16B copy; lds base must be wave-uniform (HW: base + lane*16)
__device__ __forceinline__ void gld16(const u16* g, u16* l) {
    __builtin_amdgcn_global_load_lds((const __attribute__((address_space(1))) unsigned*)g,
                                     (__attribute__((address_space(3))) unsigned*)l, 16, 0, 0);
}

// ---------- shared GEMM core: 128x128 tile, BK=64, 4 waves, static dbuf ----------
// LDS layout [128 rows][64 u16]; XOR chunk-swizzle: data chunk qd of row r lives
// at physical chunk qd^(r&7) (chunk = 16B). Store side: LDS write is linear
// (gload_lds HW), so the GLOBAL source column is pre-swizzled (rule #21 both-
// sides). ds_read side XORs the chunk with (ls&7) -> 2 lanes/bank-group = free.
// Schedule per phase: issue STAGE(next buf) FIRST, 2x(ds_read+16 MFMA), barrier.
template<int K>
__device__ __forceinline__ void gemm_core(const u16* __restrict__ A,
                                          const u16* __restrict__ B,
                                          int m0, int n0,
                                          u16 (&As)[2][8192],
                                          u16 (&Bs)[2][8192],
                                          f32x4 (&acc)[4][4]) {
    const int tid = threadIdx.x;
    const int lane = tid & 63;
    const int w = tid >> 6;
    const int wm = (w & 1) * 64, wn = (w >> 1) * 64;
    const int ls = lane & 15, lq = lane >> 4;
#pragma unroll
    for (int i = 0; i < 4; ++i)
#pragma unroll
        for (int j = 0; j < 4; ++j) acc[i][j] = (f32x4){0.f, 0.f, 0.f, 0.f};

    // staging: wave w covers rows [w*16,w*16+16) and +64; each round = 8 rows
    // x 8 chunks (64 lanes). Row for lane = +(lane>>3), physical chunk lane&7,
    // data chunk (lane&7)^(lane>>3)  [= q ^ (row&7), since row&7 = lane>>3].
    const int sr = w * 16 + (lane >> 3);
    const int sc = ((lane & 7) ^ (lane >> 3)) * 8;     // swizzled source col (u16)
    const u16* gA0 = A + (size_t)(m0 + sr) * K + sc;
    const u16* gB0 = B + (size_t)(n0 + sr) * K + sc;
    const int lo = w * 1024;                            // u16 base of wave region

    auto STG = [&](int buf, int kt) {
        gld16(gA0 + kt,                    &As[buf][lo]);          // rows +0..7
        gld16(gA0 + kt + (size_t)8 * K,    &As[buf][lo + 512]);    // rows +8..15
        gld16(gA0 + kt + (size_t)64 * K,   &As[buf][lo + 4096]);   // rows +64..71
        gld16(gA0 + kt + (size_t)72 * K,   &As[buf][lo + 4608]);   // rows +72..79
        gld16(gB0 + kt,                    &Bs[buf][lo]);
        gld16(gB0 + kt + (size_t)8 * K,    &Bs[buf][lo + 512]);
        gld16(gB0 + kt + (size_t)64 * K,   &Bs[buf][lo + 4096]);
        gld16(gB0 + kt + (size_t)72 * K,   &Bs[buf][lo + 4608]);
    };

    STG(0, 0);
    __syncthreads();

#pragma unroll 8
    for (int kt = 0; kt < K; kt += 64) {
        const int cur = (kt >> 6) & 1;          // compile-time under even unroll
        if (kt + 64 < K)
            STG(cur ^ 1, kt + 64);              // issue next-phase loads FIRST
#pragma unroll
        for (int kk = 0; kk < 2; ++kk) {
            bf16x8 af[4], bfv[4];
#pragma unroll
            for (int i = 0; i < 4; ++i)
                af[i] = *(bf16x8*)&As[cur][(wm + i * 16 + ls) * 64 +
                                           (((kk * 4 + lq) ^ (ls & 7)) * 8)];
#pragma unroll
            for (int j = 0; j < 4; ++j)
                bfv[j] = *(bf16x8*)&Bs[cur][(wn + j * 16 + ls) * 64 +
                                            (((kk * 4 + lq) ^ (ls & 7)) * 8)];
#pragma unroll
            for (int i = 0; i < 4; ++i)
#pragma unroll
                for (int j = 0; j < 4; ++j)
                    acc[i][j] = __builtin_amdgcn_mfma_f32_16x16x32_bf16(bfv[j], af[i], acc[i][j], 0, 0, 0);
        }
        if (kt + 64 < K)
            __syncthreads();                    // drains vmcnt -> next buffer ready
    }
}

// ---------- per-batch sum/sumsq over x (LN1 stats) ----------
__global__ __launch_bounds__(256) void stats_k(const float* __restrict__ src,
                                               float* __restrict__ st) {
    int b = blockIdx.y;
    const float4* p = (const float4*)(src + (size_t)b * CHW + (size_t)blockIdx.x * (CHW / 64));
    float s = 0.f, ss = 0.f;
    for (int i = threadIdx.x; i < (CHW / 64 / 4); i += 256) {
        float4 v = p[i];
        s  += v.x + v.y + v.z + v.w;
        ss += v.x * v.x + v.y * v.y + v.z * v.z + v.w * v.w;
    }
    __shared__ float r1[256], r2[256];
    int t = threadIdx.x;
    r1[t] = s; r2[t] = ss; __syncthreads();
    for (int o = 128; o > 0; o >>= 1) {
        if (t < o) { r1[t] += r1[t + o]; r2[t] += r2[t + o]; }
        __syncthreads();
    }
    if (t == 0) { atomicAdd(&st[2 * b], r1[0]); atomicAdd(&st[2 * b + 1], r2[0]); }
}

// ---------- fp32 -> bf16 flat convert (weights) ----------
__global__ __launch_bounds__(256) void cvt_k(const float* __restrict__ src,
                                             u16* __restrict__ dst, int n4) {
    int i = blockIdx.x * 256 + threadIdx.x;
    if (i >= n4) return;
    float4 v = ((const float4*)src)[i];
    ((uint2*)dst)[i] = pack_bf16x4(v.x, v.y, v.z, v.w);
}

// ---------- fp32 [c][p] -> fp32 [p][c] transpose (ln2 w/b) ----------
__global__ __launch_bounds__(256) void tr_k(const float* __restrict__ src,
                                            float* __restrict__ dst) {
    int p0 = blockIdx.x * 32, c0 = blockIdx.y * 32;
    __shared__ float T[32][33];
    int tx = threadIdx.x & 31, ty = threadIdx.x >> 5;
#pragma unroll
    for (int i = 0; i < 4; ++i)
        T[ty + i * 8][tx] = src[(size_t)(c0 + ty + i * 8) * HWS + p0 + tx];
    __syncthreads();
#pragma unroll
    for (int i = 0; i < 4; ++i)
        dst[(size_t)(p0 + ty + i * 8) * CCH + c0 + tx] = T[tx][ty + i * 8];
}

// ---------- LN1 + transpose + cvt: a[p][c] bf16 = LN1(x)[c][p] ----------
__global__ __launch_bounds__(256) void ln1t_k(const float* __restrict__ x,
                                              const float* __restrict__ w,
                                              const float* __restrict__ bb,
                                              const float* __restrict__ st,
                                              u16* __restrict__ a, int cb) {
    int p0 = blockIdx.x * 32, c0 = blockIdx.y * 32, bl = blockIdx.z;
    int b = cb + bl;
    float mean = st[2 * b] * (1.0f / CHW);
    float var  = st[2 * b + 1] * (1.0f / CHW) - mean * mean;
    float rstd = rsqrtf(var + LNEPS);
    __shared__ float T[32][33];
    int tx = threadIdx.x & 31, ty = threadIdx.x >> 5;
    const float* xb = x + (size_t)b * CHW;
#pragma unroll
    for (int i = 0; i < 4; ++i) {
        size_t o = (size_t)(c0 + ty + i * 8) * HWS + p0 + tx;
        T[ty + i * 8][tx] = (xb[o] - mean) * rstd * w[o] + bb[o];
    }
    __syncthreads();
    u16* ab = a + (size_t)bl * CHW;
#pragma unroll
    for (int i = 0; i < 4; ++i)
        ab[(size_t)(p0 + ty + i * 8) * CCH + c0 + tx] = f2bf(T[tx][ty + i * 8]);
}

// ---------- plain GEMM (QKV, ff1): Out[m][n] bf16 = A@B^T + bias, opt gelu ----------
template<int K, int ACT>
__global__ __launch_bounds__(256) void gemm_tn(const u16* __restrict__ A,
                                               const u16* __restrict__ B,
                                               const float* __restrict__ bias,
                                               u16* __restrict__ Out,
                                               int ldo, int nt) {
    __shared__ u16 As[2][8192];
    __shared__ u16 Bs[2][8192];
    const int cpx = gridDim.x >> 3;
    const int wg = ((int)blockIdx.x & 7) * cpx + ((int)blockIdx.x >> 3);
    const int m0 = (wg / nt) * 128;
    const int n0 = (wg % nt) * 128;
    f32x4 acc[4][4];
    gemm_core<K>(A, B, m0, n0, As, Bs, acc);

    const int lane = threadIdx.x & 63;
    const int w = threadIdx.x >> 6;
    const int wm = (w & 1) * 64, wn = (w >> 1) * 64;
    const int ls = lane & 15, lq = lane >> 4;
#pragma unroll
    for (int j = 0; j < 4; ++j) {
        int nb = n0 + wn + j * 16 + lq * 4;
        float4 bv = *(const float4*)&bias[nb];
#pragma unroll
        for (int i = 0; i < 4; ++i) {
            int m = m0 + wm + i * 16 + ls;
            float v0 = acc[i][j][0] + bv.x;
            float v1 = acc[i][j][1] + bv.y;
            float v2 = acc[i][j][2] + bv.z;
            float v3 = acc[i][j][3] + bv.w;
            if (ACT) { v0 = gelu_f(v0); v1 = gelu_f(v1); v2 = gelu_f(v2); v3 = gelu_f(v3); }
            *(uint2*)(Out + (size_t)m * ldo + nb) = pack_bf16x4(v0, v1, v2, v3);
        }
    }
}

// ---------- hu GEMM fused with residual + LN2 partial stats ----------
// r[p][c] = x[c][p] + (attnRaw @ huw^T + hub)[p][c]; per-block (sum,sumsq) -> pstat
// reduction arrays alias the dead staging LDS (union) to stay <=64 KB.
__global__ __launch_bounds__(256) void gemm_hu_resid(const u16* __restrict__ A,
                                                     const u16* __restrict__ B,
                                                     const float* __restrict__ bias,
                                                     float* __restrict__ r,
                                                     const float* __restrict__ x,
                                                     float* __restrict__ pstat, int cb) {
    __shared__ union {
        struct { u16 As[2][8192]; u16 Bs[2][8192]; } g;
        struct { float r1[256]; float r2[256]; } red;
    } shm;
    const int nt = 4;
    const int cpx = gridDim.x >> 3;
    const int wg = ((int)blockIdx.x & 7) * cpx + ((int)blockIdx.x >> 3);
    const int m0 = (wg / nt) * 128;
    const int n0 = (wg % nt) * 128;
    f32x4 acc[4][4];
    gemm_core<512>(A, B, m0, n0, shm.g.As, shm.g.Bs, acc);

    const int lane = threadIdx.x & 63;
    const int w = threadIdx.x >> 6;
    const int wm = (w & 1) * 64, wn = (w >> 1) * 64;
    const int ls = lane & 15, lq = lane >> 4;
    const int bl = m0 >> 12;             // batch within chunk (m0/4096)
    const int p0loc = m0 & 4095;
    const float* xb = x + (size_t)(cb + bl) * CHW;
    float* rb = r + (size_t)bl * CHW;
    float s = 0.f, ss = 0.f;
#pragma unroll
    for (int j = 0; j < 4; ++j) {
        int nb = n0 + wn + j * 16 + lq * 4;  // channel c base
        float4 bv = *(const float4*)&bias[nb];
#pragma unroll
        for (int i = 0; i < 4; ++i) {
            int p = p0loc + wm + i * 16 + ls;
            float v0 = acc[i][j][0] + bv.x + xb[(size_t)(nb + 0) * HWS + p];
            float v1 = acc[i][j][1] + bv.y + xb[(size_t)(nb + 1) * HWS + p];
            float v2 = acc[i][j][2] + bv.z + xb[(size_t)(nb + 2) * HWS + p];
            float v3 = acc[i][j][3] + bv.w + xb[(size_t)(nb + 3) * HWS + p];
            *(float4*)(rb + (size_t)p * CCH + nb) = (float4){v0, v1, v2, v3};
            s  += v0 + v1 + v2 + v3;
            ss += v0 * v0 + v1 * v1 + v2 * v2 + v3 * v3;
        }
    }
    int t = threadIdx.x;
    __syncthreads();                      // staging LDS dead beyond this point
    shm.red.r1[t] = s; shm.red.r2[t] = ss; __syncthreads();
    for (int o = 128; o > 0; o >>= 1) {
        if (t < o) { shm.red.r1[t] += shm.red.r1[t + o]; shm.red.r2[t] += shm.red.r2[t + o]; }
        __syncthreads();
    }
    if (t == 0) {
        int slot = ((p0loc >> 7) << 2) + (wg % nt);          // 0..127
        float* pp = pstat + ((size_t)(cb + bl) * 128 + slot) * 2;
        pp[0] = shm.red.r1[0]; pp[1] = shm.red.r2[0];
    }
}

// ---------- ff2 GEMM fused with final residual + transpose-out ----------
// out[c][p] = x2[p][c] + (H @ f2w^T + f2b)[p][c]; LDS-transposed coalesced store.
// Tt aliases the dead As/Bs storage via union.
__global__ __launch_bounds__(256) void gemm_ff2_final(const u16* __restrict__ A,
                                                      const u16* __restrict__ B,
                                                      const float* __restrict__ bias,
                                                      float* __restrict__ out,
                                                      const u16* __restrict__ x2,
                                                      int cb) {
    __shared__ union {
        struct { u16 As[2][8192]; u16 Bs[2][8192]; } g;
        float Tt[64][130];
    } shm;
    const int nt = 4;
    const int cpx = gridDim.x >> 3;
    const int wg = ((int)blockIdx.x & 7) * cpx + ((int)blockIdx.x >> 3);
    const int m0 = (wg / nt) * 128;
    const int n0 = (wg % nt) * 128;
    f32x4 acc[4][4];
    gemm_core<2048>(A, B, m0, n0, shm.g.As, shm.g.Bs, acc);

    const int tid = threadIdx.x;
    const int lane = tid & 63;
    const int w = tid >> 6;
    const int wm = (w & 1) * 64, wn = (w >> 1) * 64;
    const int ls = lane & 15, lq = lane >> 4;
    const int bl = m0 >> 12;
    const int p0loc = m0 & 4095;
    const u16* x2b = x2 + (size_t)bl * CHW;
    float* ob = out + (size_t)(cb + bl) * CHW;

    const int row = tid >> 2, mc = (tid & 3) * 32;
#pragma unroll
    for (int rnd = 0; rnd < 2; ++rnd) {
        __syncthreads();                 // orders As/Bs death (rnd0) / prev reads (rnd1) vs Tt writes
        if ((wn >> 6) == rnd) {
#pragma unroll
            for (int j = 0; j < 4; ++j) {
                int nloc = wn + j * 16 + lq * 4;             // 0..127 block-local c
                float4 bv = *(const float4*)&bias[n0 + nloc];
#pragma unroll
                for (int i = 0; i < 4; ++i) {
                    int m = wm + i * 16 + ls;                // block-local p
                    uint2 xr = *(const uint2*)&x2b[(size_t)(p0loc + m) * CCH + n0 + nloc];
                    u16* xp = (u16*)&xr;
                    int tr = nloc & 63;
                    shm.Tt[tr + 0][m] = acc[i][j][0] + bv.x + bf2f(xp[0]);
                    shm.Tt[tr + 1][m] = acc[i][j][1] + bv.y + bf2f(xp[1]);
                    shm.Tt[tr + 2][m] = acc[i][j][2] + bv.z + bf2f(xp[2]);
                    shm.Tt[tr + 3][m] = acc[i][j][3] + bv.w + bf2f(xp[3]);
                }
            }
        }
        __syncthreads();
        // all 256 threads: write 64 c-rows x 128 p coalesced
        float* orow = ob + (size_t)(n0 + rnd * 64 + row) * HWS + p0loc + mc;
#pragma unroll
        for (int q = 0; q < 32; q += 4)
            *(float4*)(orow + q) = *(float4*)&shm.Tt[row][mc + q];
    }
}

// ---------- softmax over Q channels (cols 0..511 of QKV rows), per pixel ----------
__global__ __launch_bounds__(256) void softmax_row_k(u16* __restrict__ QKV) {
    int m = blockIdx.x * 4 + (threadIdx.x >> 6);
    int lane = threadIdx.x & 63;
    u16* row = QKV + (size_t)m * QKVLD + lane * 8;
    uint4 raw = *(uint4*)row;
    u16* pr = (u16*)&raw;
    float v[8];
#pragma unroll
    for (int i = 0; i < 8; ++i) v[i] = bf2f(pr[i]);
    float mx = v[0];
#pragma unroll
    for (int i = 1; i < 8; ++i) mx = fmaxf(mx, v[i]);
    for (int o = 32; o > 0; o >>= 1) mx = fmaxf(mx, __shfl_xor(mx, o, 64));
    float s = 0.f;
#pragma unroll
    for (int i = 0; i < 8; ++i) { v[i] = __expf(v[i] - mx); s += v[i]; }
    for (int o = 32; o > 0; o >>= 1) s += __shfl_xor(s, o, 64);
    float inv = 1.0f / s;
#pragma unroll
    for (int i = 0; i < 8; ++i) pr[i] = f2bf(v[i] * inv);
    *(uint4*)row = raw;
}

// ---------- K-column softmax partial stats: per (b, 256-row chunk), per column ----------
__global__ __launch_bounds__(256) void kcolstat_k(const u16* __restrict__ QKV,
                                                  float* __restrict__ kpart) {
    int pc = blockIdx.x, bl = blockIdx.y;
    int cg = threadIdx.x & 63;           // column group (8 cols)
    int ps = threadIdx.x >> 6;           // p segment 0..3 (64 rows each)
    const u16* base = QKV + (size_t)bl * HWS * QKVLD + CCH + cg * 8;
    int p0 = pc * 256 + ps * 64;
    float m[8];
#pragma unroll
    for (int i = 0; i < 8; ++i) m[i] = -1e30f;
    for (int p = p0; p < p0 + 64; ++p) {
        uint4 r = *(const uint4*)(base + (size_t)p * QKVLD);
        u16* rp = (u16*)&r;
#pragma unroll
        for (int i = 0; i < 8; ++i) m[i] = fmaxf(m[i], bf2f(rp[i]));
    }
    __shared__ float red[4][512];
#pragma unroll
    for (int i = 0; i < 8; ++i) red[ps][cg * 8 + i] = m[i];
    __syncthreads();
#pragma unroll
    for (int i = 0; i < 8; ++i)
        m[i] = fmaxf(fmaxf(red[0][cg * 8 + i], red[1][cg * 8 + i]),
                     fmaxf(red[2][cg * 8 + i], red[3][cg * 8 + i]));
    __syncthreads();
    float s[8];
#pragma unroll
    for (int i = 0; i < 8; ++i) s[i] = 0.f;
    for (int p = p0; p < p0 + 64; ++p) {      // L2-hot second pass
        uint4 r = *(const uint4*)(base + (size_t)p * QKVLD);
        u16* rp = (u16*)&r;
#pragma unroll
        for (int i = 0; i < 8; ++i) s[i] += __expf(bf2f(rp[i]) - m[i]);
    }
#pragma unroll
    for (int i = 0; i < 8; ++i) red[ps][cg * 8 + i] = s[i];
    __syncthreads();
    if (ps == 0) {
        float* outp = kpart + (((size_t)bl * 16 + pc) * 512 + cg * 8) * 2;
#pragma unroll
        for (int i = 0; i < 8; ++i) {
            float sv = red[0][cg * 8 + i] + red[1][cg * 8 + i] +
                       red[2][cg * 8 + i] + red[3][cg * 8 + i];
            outp[2 * i] = m[i]; outp[2 * i + 1] = sv;
        }
    }
}

// ---------- merge 16 chunk partials -> (max, 1/sum) per column ----------
__global__ __launch_bounds__(256) void kcolmerge_k(const float* __restrict__ kpart,
                                                   float* __restrict__ kstat) {
    int bl = blockIdx.x;
#pragma unroll
    for (int j = 0; j < 2; ++j) {
        int col = threadIdx.x * 2 + j;
        float m = -1e30f;
        for (int pc = 0; pc < 16; ++pc)
            m = fmaxf(m, kpart[(((size_t)bl * 16 + pc) * 512 + col) * 2]);
        float s = 0.f;
        for (int pc = 0; pc < 16; ++pc) {
            const float* p = kpart + (((size_t)bl * 16 + pc) * 512 + col) * 2;
            s += p[1] * __expf(p[0] - m);
        }
        kstat[((size_t)bl * 512 + col) * 2]     = m;
        kstat[((size_t)bl * 512 + col) * 2 + 1] = 1.0f / s;
    }
}

// ---------- KV[b,h,k,v] = sum_p softmaxK[p][hk]*V[p][hv] (atomic over 16 p-chunks) ----------
__global__ __launch_bounds__(256) void kv_k2(const u16* __restrict__ QKV,
                                             const float* __restrict__ kstat,
                                             float* __restrict__ KV) {
    int pc = blockIdx.x, h = blockIdx.y, bl = blockIdx.z;
    const u16* kbase = QKV + (size_t)bl * HWS * QKVLD + CCH + h * HD;
    const u16* vbase = kbase + CCH;
    float* kvb = KV + ((size_t)bl * NHEAD + h) * (HD * HD);
    __shared__ float Ks[64][65], Vs[64][65];
    __shared__ float Ms[64], Is[64];
    int tid = threadIdx.x;
    if (tid < 64) {
        const float* sp = kstat + ((size_t)bl * 512 + h * HD + tid) * 2;
        Ms[tid] = sp[0]; Is[tid] = sp[1];
    }
    int tk = tid >> 4, tv = tid & 15;
    float acc[4][4];
#pragma unroll
    for (int i = 0; i < 4; ++i)
#pragma unroll
        for (int j = 0; j < 4; ++j) acc[i][j] = 0.f;

    for (int s = 0; s < 4; ++s) {
        int pbase = pc * 256 + s * 64;
        __syncthreads();
#pragma unroll
        for (int j = 0; j < 2; ++j) {
            int li = tid + j * 256;
            int pl = li >> 3, c8 = (li & 7) * 8;
            uint4 kr = *(const uint4*)(kbase + (size_t)(pbase + pl) * QKVLD + c8);
            uint4 vr = *(const uint4*)(vbase + (size_t)(pbase + pl) * QKVLD + c8);
            u16* kp = (u16*)&kr; u16* vp = (u16*)&vr;
#pragma unroll
            for (int t = 0; t < 8; ++t) {
                Ks[pl][c8 + t] = __expf(bf2f(kp[t]) - Ms[c8 + t]) * Is[c8 + t];
                Vs[pl][c8 + t] = bf2f(vp[t]);
            }
        }
        __syncthreads();
#pragma unroll 4
        for (int p = 0; p < 64; ++p) {
            float ka[4], va[4];
#pragma unroll
            for (int i = 0; i < 4; ++i) { ka[i] = Ks[p][tk * 4 + i]; va[i] = Vs[p][tv * 4 + i]; }
#pragma unroll
            for (int i = 0; i < 4; ++i)
#pragma unroll
                for (int j = 0; j < 4; ++j) acc[i][j] += ka[i] * va[j];
        }
    }
#pragma unroll
    for (int i = 0; i < 4; ++i)
#pragma unroll
        for (int j = 0; j < 4; ++j)
            atomicAdd(&kvb[(size_t)(tk * 4 + i) * HD + tv * 4 + j], acc[i][j]);
}

// ---------- attnRaw[p][hv] bf16 = sum_k KV[k][v]*Q[p][hk] ----------
__global__ __launch_bounds__(256) void attn_k2(const u16* __restrict__ QKV,
                                               const float* __restrict__ KV,
                                               u16* __restrict__ attnRaw) {
    int pt = blockIdx.x, h = blockIdx.y, bl = blockIdx.z;
    const u16* qbase = QKV + (size_t)bl * HWS * QKVLD + h * HD;
    const float* kvb = KV + ((size_t)bl * NHEAD + h) * (HD * HD);
    __shared__ float KVs[64][68], Qs[64][68];
    int tid = threadIdx.x;
#pragma unroll
    for (int j = 0; j < 4; ++j) {
        int li = tid + j * 256;
        int k = li >> 4, c4 = (li & 15) * 4;
        *(float4*)&KVs[k][c4] = *(const float4*)(kvb + (size_t)k * HD + c4);
    }
#pragma unroll
    for (int j = 0; j < 2; ++j) {
        int li = tid + j * 256;
        int pl = li >> 3, c8 = (li & 7) * 8;
        uint4 qr = *(const uint4*)(qbase + (size_t)(pt * 64 + pl) * QKVLD + c8);
        u16* qp = (u16*)&qr;
#pragma unroll
        for (int t = 0; t < 8; ++t) Qs[pl][c8 + t] = bf2f(qp[t]);
    }
    __syncthreads();
    int tp = tid >> 4, tv = tid & 15;
    float acc[4][4];
#pragma unroll
    for (int i = 0; i < 4; ++i)
#pragma unroll
        for (int j = 0; j < 4; ++j) acc[i][j] = 0.f;
#pragma unroll 4
    for (int k = 0; k < 64; ++k) {
        float qa[4], kv4[4];
#pragma unroll
        for (int i = 0; i < 4; ++i) { qa[i] = Qs[tp * 4 + i][k]; kv4[i] = KVs[k][tv * 4 + i]; }
#pragma unroll
        for (int i = 0; i < 4; ++i)
#pragma unroll
            for (int j = 0; j < 4; ++j) acc[i][j] += qa[i] * kv4[j];
    }
#pragma unroll
    for (int i = 0; i < 4; ++i) {
        *(uint2*)(attnRaw + (size_t)(bl * HWS + pt * 64 + tp * 4 + i) * CCH + h * HD + tv * 4) =
            pack_bf16x4(acc[i][0], acc[i][1], acc[i][2], acc[i][3]);
    }
}

// ---------- reduce 128 per-block partials -> LN2 stats ----------
__global__ __launch_bounds__(128) void red2_k(const float* __restrict__ pstat,
                                              float* __restrict__ st, int cb) {
    int b = cb + blockIdx.x;
    const float* p = pstat + (size_t)b * 256;
    int t = threadIdx.x;
    float s = p[2 * t], ss = p[2 * t + 1];
    for (int o = 32; o > 0; o >>= 1) { s += __shfl_down(s, o, 64); ss += __shfl_down(ss, o, 64); }
    __shared__ float sh[4];
    if ((t & 63) == 0) { sh[(t >> 6) * 2] = s; sh[(t >> 6) * 2 + 1] = ss; }
    __syncthreads();
    if (t == 0) { st[32 + 2 * b] = sh[0] + sh[2]; st[32 + 2 * b + 1] = sh[1] + sh[3]; }
}

// ---------- x2 bf16 [p][c] = LN2(r) ----------
__global__ __launch_bounds__(256) void ln2a_k(const float* __restrict__ r,
                                              const float* __restrict__ w2t,
                                              const float* __restrict__ b2t,
                                              const float* __restrict__ st,
                                              u16* __restrict__ x2, int cb) {
    size_t i4 = (size_t)blockIdx.x * 256 + threadIdx.x;
    int bl = (int)(i4 / (CHW / 4));
    int b = cb + bl;
    size_t off4 = i4 % (CHW / 4);
    float mean = st[32 + 2 * b] * (1.0f / CHW);
    float var  = st[32 + 2 * b + 1] * (1.0f / CHW) - mean * mean;
    float rstd = rsqrtf(var + LNEPS);
    float4 v  = ((const float4*)(r + (size_t)bl * CHW))[off4];
    float4 wv = ((const float4*)w2t)[off4];
    float4 bv = ((const float4*)b2t)[off4];
    ((uint2*)(x2 + (size_t)bl * CHW))[off4] =
        pack_bf16x4((v.x - mean) * rstd * wv.x + bv.x,
                    (v.y - mean) * rstd * wv.y + bv.y,
                    (v.z - mean) * rstd * wv.z + bv.z,
                    (v.w - mean) * rstd * wv.w + bv.w);
}

extern "C" void kernel_launch(void* const* d_in, const int* in_sizes, int n_in,
                              void* d_out, int out_size, void* d_ws, size_t ws_size,
                              hipStream_t stream) {
    const float* x    = (const float*)d_in[0];
    const float* ln1w = (const float*)d_in[1];
    const float* ln1b = (const float*)d_in[2];
    const float* qw   = (const float*)d_in[3];
    const float* qb   = (const float*)d_in[4];
    const float* kw   = (const float*)d_in[5];
    const float* kb   = (const float*)d_in[6];
    const float* vw   = (const float*)d_in[7];
    const float* vb   = (const float*)d_in[8];
    const float* huw  = (const float*)d_in[9];
    const float* hub  = (const float*)d_in[10];
    const float* ln2w = (const float*)d_in[11];
    const float* ln2b = (const float*)d_in[12];
    const float* f1w  = (const float*)d_in[13];
    const float* f1b  = (const float*)d_in[14];
    const float* f2w  = (const float*)d_in[15];
    const float* f2b  = (const float*)d_in[16];
    float* out = (float*)d_out;
    float* ws = (float*)d_ws;

    // fixed ws region (floats)
    float* stats = ws;                      // 64
    float* qkvb  = ws + 64;                 // 1536
    u16*   wqkv  = (u16*)(ws + 1600);       // 1536x512 bf16 -> 393216 f
    u16*   whu   = (u16*)(ws + 394816);     // 512x512        -> 131072 f
    u16*   wf1   = (u16*)(ws + 525888);     // 2048x512       -> 524288 f
    u16*   wf2   = (u16*)(ws + 1050176);    // 512x2048       -> 524288 f
    float* w2t   = ws + 1574464;            // 2097152 f
    float* b2t   = ws + 3671616;            // 2097152 f
    float* pstat = ws + 5768768;            // 16*128*2 = 4096 f (LN2 partials)
    float* kpart = ws + 5834304;            // 16*16*512*2 = 262144 f (K col partials)
    float* kstat = ws + 6096448;            // 16*512*2 = 16384 f (K col m,inv)
    float* kvbuf = ws + 6112832;            // G*32768 f

    // chunk size G: fixed + G*(32768 + 2.5*CHW) floats
    int G = 16;
    while (G > 1 && (6112832ull + (size_t)G * 5275648ull) * 4ull > ws_size) G >>= 1;
    const int nch = BATCH / G;
    const size_t U = (size_t)G * CHW;       // chunk elems

    float* R       = kvbuf + (size_t)G * 32768;
    u16*   a_bf    = (u16*)R;               // CHWg bf16 (attnRaw; later x2bf)
    u16*   QKVb    = (u16*)(R + U / 2);     // 3*CHWg bf16
    float* rbuf    = R + 3 * U / 2;         // CHWg f32
    u16*   x2bf    = (u16*)R;               // CHWg bf16 (overlays a_bf)
    u16*   Hbuf    = (u16*)(R + U / 2);     // 4*CHWg bf16 (overlays QKVb)

    hipMemsetAsync(stats, 0, 64 * sizeof(float), stream);

    // weight conversions (every call; inputs restored by harness each iter)
    cvt_k<<<dim3(256), 256, 0, stream>>>(qw, wqkv, 65536);
    cvt_k<<<dim3(256), 256, 0, stream>>>(kw, wqkv + 262144, 65536);
    cvt_k<<<dim3(256), 256, 0, stream>>>(vw, wqkv + 524288, 65536);
    cvt_k<<<dim3(256), 256, 0, stream>>>(huw, whu, 65536);
    cvt_k<<<dim3(1024), 256, 0, stream>>>(f1w, wf1, 262144);
    cvt_k<<<dim3(1024), 256, 0, stream>>>(f2w, wf2, 262144);
    tr_k<<<dim3(128, 16), 256, 0, stream>>>(ln2w, w2t);
    tr_k<<<dim3(128, 16), 256, 0, stream>>>(ln2b, b2t);
    hipMemcpyAsync(qkvb,        qb, 512 * sizeof(float), hipMemcpyDeviceToDevice, stream);
    hipMemcpyAsync(qkvb + 512,  kb, 512 * sizeof(float), hipMemcpyDeviceToDevice, stream);
    hipMemcpyAsync(qkvb + 1024, vb, 512 * sizeof(float), hipMemcpyDeviceToDevice, stream);

    stats_k<<<dim3(64, BATCH), 256, 0, stream>>>(x, stats);

    for (int g = 0; g < nch; ++g) {
        const int cb = g * G;
        const int mt = G * 32;   // m-tiles (M = G*4096)
        // LN1 + transpose + cvt -> a[p][c] bf16
        ln1t_k<<<dim3(128, 16, G), 256, 0, stream>>>(x, ln1w, ln1b, stats, a_bf, cb);
        // fused QKV GEMM: [G*4096 x 512] x [1536 x 512]^T -> bf16 [m][1536]
        gemm_tn<512, 0><<<dim3(mt * 12), 256, 0, stream>>>(a_bf, wqkv, qkvb, QKVb, QKVLD, 12);
        softmax_row_k<<<dim3(G * 1024), 256, 0, stream>>>(QKVb);
        // K column softmax stats (normalization fused into kv_k2)
        kcolstat_k<<<dim3(16, G), 256, 0, stream>>>(QKVb, kpart);
        kcolmerge_k<<<dim3(G), 256, 0, stream>>>(kpart, kstat);
        hipMemsetAsync(kvbuf, 0, (size_t)G * 32768 * sizeof(float), stream);
        kv_k2<<<dim3(16, NHEAD, G), 256, 0, stream>>>(QKVb, kstat, kvbuf);
        attn_k2<<<dim3(64, NHEAD, G), 256, 0, stream>>>(QKVb, kvbuf, a_bf);  // attnRaw over a
        // hu GEMM fused with residual + LN2 stats -> rbuf
        gemm_hu_resid<<<dim3(mt * 4), 256, 0, stream>>>(a_bf, whu, hub, rbuf, x, pstat, cb);
        red2_k<<<dim3(G), 128, 0, stream>>>(pstat, stats, cb);
        ln2a_k<<<dim3(G * 2048), 256, 0, stream>>>(rbuf, w2t, b2t, stats, x2bf, cb);
        // ff1 GEMM + gelu -> H bf16 [m][2048]
        gemm_tn<512, 1><<<dim3(mt * 16), 256, 0, stream>>>(x2bf, wf1, f1b, Hbuf, DHFF, 16);
        // ff2 GEMM fused with final residual + transpose -> out
        gemm_ff2_final<<<dim3(mt * 4), 256, 0, stream>>>(Hbuf, wf2, f2b, out, x2bf, cb);
    }
}